// Round 1
// baseline (1013.556 us; speedup 1.0000x reference)
//
#include <hip/hip_runtime.h>

// GCN node regressor: 3x GCNConv(relu) + linear readout, f32.
// N=100000 nodes, E=1600000 edges, IN=128, HID=64.
//
// Strategy:
//  - Build CSR (indexed by dst) once per launch: histogram + scan + fill.
//    Aggregation is then a pure gather (no float atomics).
//  - GEMM folds dis[i] into epilogue: G = dis * (H @ W). Edge contribution
//    to node i is dis[i]*G[src], self term dis[i]*G[i].
//  - agg: one wave per node, lane = channel; fused bias+relu; final layer
//    fuses the [64]->1 readout via wave reduce.

#define NN 100000
#define NE 1600000
#define HID 64

// ---------- edge dtype detection (int32 vs int64 canonicalization) ----------
__global__ __launch_bounds__(256) void detect_kernel(const int* __restrict__ ei,
                                                     int* __restrict__ flag) {
  __shared__ int nz;
  if (threadIdx.x == 0) nz = 0;
  __syncthreads();
  // For int64 little-endian data with values in [0,1e5), every odd 32-bit
  // word (high word) is 0. For int32 data these are random node ids.
  if (ei[2 * threadIdx.x + 1] != 0) atomicAdd(&nz, 1);
  __syncthreads();
  if (threadIdx.x == 0) *flag = (nz == 0) ? 1 : 0;  // 1 => int64 layout
}

__device__ __forceinline__ int load_src(const int* ei, int is64, int e) {
  return is64 ? ei[(size_t)2 * e] : ei[e];
}
__device__ __forceinline__ int load_dst(const int* ei, int is64, int e) {
  return is64 ? ei[(size_t)2 * NE + (size_t)2 * e] : ei[(size_t)NE + e];
}

// ---------- CSR build ----------
__global__ __launch_bounds__(256) void zero_kernel(int* __restrict__ a, int* __restrict__ b) {
  int i = blockIdx.x * 256 + threadIdx.x;
  if (i < NN) { a[i] = 0; b[i] = 0; }
}

__global__ __launch_bounds__(256) void hist_kernel(const int* __restrict__ ei,
                                                   const int* __restrict__ flag,
                                                   int* __restrict__ cnt) {
  int e = blockIdx.x * 256 + threadIdx.x;
  if (e >= NE) return;
  int is64 = *flag;
  atomicAdd(&cnt[load_dst(ei, is64, e)], 1);
}

__global__ __launch_bounds__(256) void scan1_kernel(const int* __restrict__ cnt,
                                                    int* __restrict__ rs,
                                                    int* __restrict__ bsum) {
  __shared__ int tmp[256];
  int i = blockIdx.x * 256 + threadIdx.x;
  int v = (i < NN) ? cnt[i] : 0;
  int x = v;
  tmp[threadIdx.x] = x;
  __syncthreads();
  for (int off = 1; off < 256; off <<= 1) {
    int y = (threadIdx.x >= off) ? tmp[threadIdx.x - off] : 0;
    __syncthreads();
    x += y;
    tmp[threadIdx.x] = x;
    __syncthreads();
  }
  if (i < NN) rs[i] = x - v;                 // block-local exclusive
  if (threadIdx.x == 255) bsum[blockIdx.x] = x;  // block total
}

__global__ __launch_bounds__(512) void scan2_kernel(int* __restrict__ bsum, int nb,
                                                    int* __restrict__ total_out) {
  __shared__ int tmp[512];
  int v = (threadIdx.x < nb) ? bsum[threadIdx.x] : 0;
  int x = v;
  tmp[threadIdx.x] = x;
  __syncthreads();
  for (int off = 1; off < 512; off <<= 1) {
    int y = (threadIdx.x >= off) ? tmp[threadIdx.x - off] : 0;
    __syncthreads();
    x += y;
    tmp[threadIdx.x] = x;
    __syncthreads();
  }
  if (threadIdx.x < nb) bsum[threadIdx.x] = x - v;  // exclusive block offsets
  if (threadIdx.x == 511) *total_out = x;           // rs[NN] = E
}

__global__ __launch_bounds__(256) void scan3_kernel(int* __restrict__ rs,
                                                    const int* __restrict__ bsum) {
  int i = blockIdx.x * 256 + threadIdx.x;
  if (i < NN) rs[i] += bsum[blockIdx.x];
}

__global__ __launch_bounds__(256) void dis_kernel(const int* __restrict__ cnt,
                                                  float* __restrict__ dis) {
  int i = blockIdx.x * 256 + threadIdx.x;
  if (i < NN) dis[i] = rsqrtf((float)cnt[i] + 1.0f);  // +1 self-loop
}

__global__ __launch_bounds__(256) void fill_kernel(const int* __restrict__ ei,
                                                   const int* __restrict__ flag,
                                                   const int* __restrict__ rs,
                                                   int* __restrict__ fil,
                                                   int* __restrict__ csr) {
  int e = blockIdx.x * 256 + threadIdx.x;
  if (e >= NE) return;
  int is64 = *flag;
  int s = load_src(ei, is64, e);
  int d = load_dst(ei, is64, e);
  int pos = rs[d] + atomicAdd(&fil[d], 1);
  csr[pos] = s;
}

// ---------- weight transpose (Wt[c][k] = W[k][c], uniform scalar loads) ----------
__global__ __launch_bounds__(256) void prep_kernel(const float* __restrict__ W1,
                                                   const float* __restrict__ W2,
                                                   const float* __restrict__ W3,
                                                   float* __restrict__ Wt1,
                                                   float* __restrict__ Wt2,
                                                   float* __restrict__ Wt3) {
  int t = blockIdx.x * 256 + threadIdx.x;
  if (t < 8192) {
    int c = t >> 7, k = t & 127;
    Wt1[c * 128 + k] = W1[k * 64 + c];
  } else if (t < 12288) {
    int u = t - 8192; int c = u >> 6, k = u & 63;
    Wt2[c * 64 + k] = W2[k * 64 + c];
  } else if (t < 16384) {
    int u = t - 12288; int c = u >> 6, k = u & 63;
    Wt3[c * 64 + k] = W3[k * 64 + c];
  }
}

// ---------- GEMM: G[r][c] = dis[r] * sum_k X[r][k] * Wt[c][k] ----------
// One thread per row; acc[64] in VGPRs; W reads are wave-uniform -> s_load.
template <int K>
__global__ __launch_bounds__(256) void gemm_kernel(const float* __restrict__ X,
                                                   const float* __restrict__ Wt,
                                                   const float* __restrict__ dis,
                                                   float* __restrict__ G) {
  int r = blockIdx.x * 256 + threadIdx.x;
  if (r >= NN) return;
  const float* xrow = X + (size_t)r * K;
  float acc[HID];
#pragma unroll
  for (int c = 0; c < HID; ++c) acc[c] = 0.f;
#pragma unroll 1
  for (int k0 = 0; k0 < K; k0 += 8) {
    float4 xa = *reinterpret_cast<const float4*>(xrow + k0);
    float4 xb = *reinterpret_cast<const float4*>(xrow + k0 + 4);
    float xr[8] = {xa.x, xa.y, xa.z, xa.w, xb.x, xb.y, xb.z, xb.w};
#pragma unroll
    for (int c = 0; c < HID; ++c) {
      const float* w = Wt + c * K + k0;  // wave-uniform address
#pragma unroll
      for (int j = 0; j < 8; ++j) acc[c] = fmaf(xr[j], w[j], acc[c]);
    }
  }
  float di = dis[r];
  float* grow = G + (size_t)r * HID;
#pragma unroll
  for (int c = 0; c < HID; c += 4) {
    float4 ov = make_float4(acc[c] * di, acc[c + 1] * di, acc[c + 2] * di, acc[c + 3] * di);
    *reinterpret_cast<float4*>(grow + c) = ov;
  }
}

// ---------- aggregation: one wave per node, lane = channel ----------
// out[i][c] = relu(dis[i] * (G[i][c] + sum_e G[csr[e]][c]) + b[c])
// FINAL: additionally out1[i] = sum_c h[i][c]*Wout[c] + bout  (wave reduce)
template <bool FINAL>
__global__ __launch_bounds__(256) void agg_kernel(const float* __restrict__ G,
                                                  const int* __restrict__ rs,
                                                  const int* __restrict__ csr,
                                                  const float* __restrict__ dis,
                                                  const float* __restrict__ bias,
                                                  const float* __restrict__ Wout,
                                                  const float* __restrict__ bout,
                                                  float* __restrict__ Out) {
  int gtid = blockIdx.x * 256 + threadIdx.x;
  int i = gtid >> 6;
  int lane = threadIdx.x & 63;
  if (i >= NN) return;
  int s0 = rs[i], s1 = rs[i + 1];
  float acc = G[(size_t)i * HID + lane];  // self-loop term
  for (int e = s0; e < s1; ++e) {
    int s = csr[e];  // wave-uniform broadcast load
    acc += G[(size_t)s * HID + lane];
  }
  float val = fmaxf(dis[i] * acc + bias[lane], 0.0f);
  if (!FINAL) {
    Out[(size_t)i * HID + lane] = val;
  } else {
    float r = val * Wout[lane];
#pragma unroll
    for (int off = 32; off > 0; off >>= 1) r += __shfl_down(r, off);
    if (lane == 0) Out[i] = r + bout[0];
  }
}

extern "C" void kernel_launch(void* const* d_in, const int* in_sizes, int n_in,
                              void* d_out, int out_size, void* d_ws, size_t ws_size,
                              hipStream_t stream) {
  const float* x  = (const float*)d_in[0];
  const int*   ei = (const int*)d_in[1];
  const float* W1 = (const float*)d_in[2];
  const float* b1 = (const float*)d_in[3];
  const float* W2 = (const float*)d_in[4];
  const float* b2 = (const float*)d_in[5];
  const float* W3 = (const float*)d_in[6];
  const float* b3 = (const float*)d_in[7];
  const float* Wo = (const float*)d_in[8];
  const float* bo = (const float*)d_in[9];
  float* out = (float*)d_out;

  char* ws = (char*)d_ws;
  size_t o = 0;
  auto alloc = [&](size_t bytes) {
    size_t r = o;
    o = (o + bytes + 255) & ~(size_t)255;
    return r;
  };
  int*   cnt  = (int*)(ws + alloc((size_t)NN * 4));
  int*   fil  = (int*)(ws + alloc((size_t)NN * 4));
  int*   rs   = (int*)(ws + alloc((size_t)(NN + 1) * 4));
  int*   bsum = (int*)(ws + alloc(512 * 4));
  float* dis  = (float*)(ws + alloc((size_t)NN * 4));
  int*   flag = (int*)(ws + alloc(256));
  float* Wt1  = (float*)(ws + alloc(8192 * 4));
  float* Wt2  = (float*)(ws + alloc(4096 * 4));
  float* Wt3  = (float*)(ws + alloc(4096 * 4));
  int*   csr  = (int*)(ws + alloc((size_t)NE * 4));
  float* A    = (float*)(ws + alloc((size_t)NN * HID * 4));
  float* B    = (float*)(ws + alloc((size_t)NN * HID * 4));
  (void)ws_size; (void)in_sizes; (void)n_in; (void)out_size;

  const int NBLK = (NN + 255) / 256;   // 391
  const int EBLK = (NE + 255) / 256;   // 6250
  const int ABLK = (NN * HID) / 256;   // 25000

  zero_kernel<<<NBLK, 256, 0, stream>>>(cnt, fil);
  detect_kernel<<<1, 256, 0, stream>>>(ei, flag);
  hist_kernel<<<EBLK, 256, 0, stream>>>(ei, flag, cnt);
  scan1_kernel<<<NBLK, 256, 0, stream>>>(cnt, rs, bsum);
  scan2_kernel<<<1, 512, 0, stream>>>(bsum, NBLK, rs + NN);
  scan3_kernel<<<NBLK, 256, 0, stream>>>(rs, bsum);
  dis_kernel<<<NBLK, 256, 0, stream>>>(cnt, dis);
  fill_kernel<<<EBLK, 256, 0, stream>>>(ei, flag, rs, fil, csr);
  prep_kernel<<<64, 256, 0, stream>>>(W1, W2, W3, Wt1, Wt2, Wt3);

  // Layer 1: in = x (K=128)
  gemm_kernel<128><<<NBLK, 256, 0, stream>>>(x, Wt1, dis, A);
  agg_kernel<false><<<ABLK, 256, 0, stream>>>(A, rs, csr, dis, b1, nullptr, nullptr, B);
  // Layer 2
  gemm_kernel<64><<<NBLK, 256, 0, stream>>>(B, Wt2, dis, A);
  agg_kernel<false><<<ABLK, 256, 0, stream>>>(A, rs, csr, dis, b2, nullptr, nullptr, B);
  // Layer 3 + fused readout
  gemm_kernel<64><<<NBLK, 256, 0, stream>>>(B, Wt3, dis, A);
  agg_kernel<true><<<ABLK, 256, 0, stream>>>(A, rs, csr, dis, b3, Wo, bo, out);
}

// Round 4
// 593.689 us; speedup vs baseline: 1.7072x; 1.7072x over previous
//
#include <hip/hip_runtime.h>

// GCN node regressor: 3x GCNConv(relu) + linear readout, f32.
// N=100000 nodes, E=1600000 edges, IN=128, HID=64.
//
//  - CSR build (hist+scan+fill) once per launch -> aggregation is pure gather.
//  - GEMM v2: 128x64 block tile, 8x4 register tile, K-chunked LDS staging
//    (XsT transposed + Ws). dis[r] folded into GEMM epilogue.
//  - agg: one wave per node, lane = channel; edge loop unrolled x8 for MLP;
//    fused bias+relu; final layer fuses [64]->1 readout via wave reduce.

#define NN 100000
#define NE 1600000
#define HID 64

// ---------- edge dtype detection (int32 vs int64 canonicalization) ----------
__global__ __launch_bounds__(256) void detect_kernel(const int* __restrict__ ei,
                                                     int* __restrict__ flag) {
  __shared__ int nz;
  if (threadIdx.x == 0) nz = 0;
  __syncthreads();
  if (ei[2 * threadIdx.x + 1] != 0) atomicAdd(&nz, 1);
  __syncthreads();
  if (threadIdx.x == 0) *flag = (nz == 0) ? 1 : 0;  // 1 => int64 layout
}

__device__ __forceinline__ int load_src(const int* ei, int is64, int e) {
  return is64 ? ei[(size_t)2 * e] : ei[e];
}
__device__ __forceinline__ int load_dst(const int* ei, int is64, int e) {
  return is64 ? ei[(size_t)2 * NE + (size_t)2 * e] : ei[(size_t)NE + e];
}

// ---------- CSR build ----------
__global__ __launch_bounds__(256) void zero_kernel(int* __restrict__ a, int* __restrict__ b) {
  int i = blockIdx.x * 256 + threadIdx.x;
  if (i < NN) { a[i] = 0; b[i] = 0; }
}

__global__ __launch_bounds__(256) void hist_kernel(const int* __restrict__ ei,
                                                   const int* __restrict__ flag,
                                                   int* __restrict__ cnt) {
  int e = blockIdx.x * 256 + threadIdx.x;
  if (e >= NE) return;
  int is64 = *flag;
  atomicAdd(&cnt[load_dst(ei, is64, e)], 1);
}

__global__ __launch_bounds__(256) void scan1_kernel(const int* __restrict__ cnt,
                                                    int* __restrict__ rs,
                                                    int* __restrict__ bsum) {
  __shared__ int tmp[256];
  int i = blockIdx.x * 256 + threadIdx.x;
  int v = (i < NN) ? cnt[i] : 0;
  int x = v;
  tmp[threadIdx.x] = x;
  __syncthreads();
  for (int off = 1; off < 256; off <<= 1) {
    int y = (threadIdx.x >= off) ? tmp[threadIdx.x - off] : 0;
    __syncthreads();
    x += y;
    tmp[threadIdx.x] = x;
    __syncthreads();
  }
  if (i < NN) rs[i] = x - v;
  if (threadIdx.x == 255) bsum[blockIdx.x] = x;
}

__global__ __launch_bounds__(512) void scan2_kernel(int* __restrict__ bsum, int nb,
                                                    int* __restrict__ total_out) {
  __shared__ int tmp[512];
  int v = (threadIdx.x < nb) ? bsum[threadIdx.x] : 0;
  int x = v;
  tmp[threadIdx.x] = x;
  __syncthreads();
  for (int off = 1; off < 512; off <<= 1) {
    int y = (threadIdx.x >= off) ? tmp[threadIdx.x - off] : 0;
    __syncthreads();
    x += y;
    tmp[threadIdx.x] = x;
    __syncthreads();
  }
  if (threadIdx.x < nb) bsum[threadIdx.x] = x - v;
  if (threadIdx.x == 511) *total_out = x;
}

__global__ __launch_bounds__(256) void scan3_kernel(int* __restrict__ rs,
                                                    const int* __restrict__ bsum) {
  int i = blockIdx.x * 256 + threadIdx.x;
  if (i < NN) rs[i] += bsum[blockIdx.x];
}

__global__ __launch_bounds__(256) void dis_kernel(const int* __restrict__ cnt,
                                                  float* __restrict__ dis) {
  int i = blockIdx.x * 256 + threadIdx.x;
  if (i < NN) dis[i] = rsqrtf((float)cnt[i] + 1.0f);
}

__global__ __launch_bounds__(256) void fill_kernel(const int* __restrict__ ei,
                                                   const int* __restrict__ flag,
                                                   const int* __restrict__ rs,
                                                   int* __restrict__ fil,
                                                   int* __restrict__ csr) {
  int e = blockIdx.x * 256 + threadIdx.x;
  if (e >= NE) return;
  int is64 = *flag;
  int s = load_src(ei, is64, e);
  int d = load_dst(ei, is64, e);
  int pos = rs[d] + atomicAdd(&fil[d], 1);
  csr[pos] = s;
}

// ---------- GEMM v2: G[r][c] = dis[r] * sum_k X[r][k] * W[k][c] ----------
// Block tile 128 rows x 64 cols, thread tile 8x4, K chunked by 32.
// W is used in its NATIVE [K][64] layout (Ws[k][c0..c0+3] is contiguous).
#define KT 32
#define PADX 2   // XsT row pad (floats)
#define PADW 4   // Ws row pad (floats)

template <int K>
__global__ __launch_bounds__(256) void gemm_kernel(const float* __restrict__ X,
                                                   const float* __restrict__ W,
                                                   const float* __restrict__ dis,
                                                   float* __restrict__ G) {
  __shared__ float XsT[KT][128 + PADX];
  __shared__ float Ws[KT][64 + PADW];
  const int t = threadIdx.x;
  const int row0 = blockIdx.x * 128;
  const int r_grp = t & 15;        // 16 groups of 8 rows
  const int c_grp = t >> 4;        // 16 groups of 4 cols
  const int r0 = r_grp * 8;
  const int c0 = c_grp * 4;

  float acc[8][4];
#pragma unroll
  for (int i = 0; i < 8; ++i)
#pragma unroll
    for (int j = 0; j < 4; ++j) acc[i][j] = 0.f;

  for (int k0 = 0; k0 < K; k0 += KT) {
    __syncthreads();  // protect previous chunk's reads
    // stage XsT[kk][r] = X[row0+r][k0+kk]; 128 rows x 32 k = 1024 float4
    {
#pragma unroll
      for (int it = 0; it < 4; ++it) {
        int idx = it * 256 + t;          // 0..1023
        int r = idx >> 3;                // 0..127
        int kq = (idx & 7) << 2;         // 0,4,...,28
        int rr = row0 + r;
        if (rr >= NN) rr = NN - 1;
        float4 v = *reinterpret_cast<const float4*>(X + (size_t)rr * K + k0 + kq);
        XsT[kq + 0][r] = v.x;
        XsT[kq + 1][r] = v.y;
        XsT[kq + 2][r] = v.z;
        XsT[kq + 3][r] = v.w;
      }
    }
    // stage Ws[kk][c] = W[(k0+kk)*64 + c]; 32 k x 16 float4 = 512
    {
#pragma unroll
      for (int it = 0; it < 2; ++it) {
        int idx = it * 256 + t;          // 0..511
        int kk = idx >> 4;               // 0..31
        int c4 = (idx & 15) << 2;        // 0..60
        float4 v = *reinterpret_cast<const float4*>(W + (size_t)(k0 + kk) * 64 + c4);
        *reinterpret_cast<float4*>(&Ws[kk][c4]) = v;
      }
    }
    __syncthreads();

#pragma unroll 4
    for (int kk = 0; kk < KT; ++kk) {
      float4 w4 = *reinterpret_cast<const float4*>(&Ws[kk][c0]);
      float4 xa = *reinterpret_cast<const float4*>(&XsT[kk][r0]);
      float4 xb = *reinterpret_cast<const float4*>(&XsT[kk][r0 + 4]);
      float xr[8] = {xa.x, xa.y, xa.z, xa.w, xb.x, xb.y, xb.z, xb.w};
      float wr[4] = {w4.x, w4.y, w4.z, w4.w};
#pragma unroll
      for (int i = 0; i < 8; ++i)
#pragma unroll
        for (int j = 0; j < 4; ++j) acc[i][j] = fmaf(xr[i], wr[j], acc[i][j]);
    }
  }

  // epilogue: scale by dis[r], store float4
#pragma unroll
  for (int i = 0; i < 8; ++i) {
    int r = row0 + r0 + i;
    if (r < NN) {
      float d = dis[r];
      float4 ov = make_float4(acc[i][0] * d, acc[i][1] * d, acc[i][2] * d, acc[i][3] * d);
      *reinterpret_cast<float4*>(G + (size_t)r * HID + c0) = ov;
    }
  }
}

// ---------- aggregation: one wave per node, lane = channel ----------
// out[i][c] = relu(dis[i] * (G[i][c] + sum_e G[csr[e]][c]) + b[c])
// FINAL: out1[i] = sum_c h[i][c]*Wout[c] + bout (wave reduce)
template <bool FINAL>
__global__ __launch_bounds__(256) void agg_kernel(const float* __restrict__ G,
                                                  const int* __restrict__ rs,
                                                  const int* __restrict__ csr,
                                                  const float* __restrict__ dis,
                                                  const float* __restrict__ bias,
                                                  const float* __restrict__ Wout,
                                                  const float* __restrict__ bout,
                                                  float* __restrict__ Out) {
  int gtid = blockIdx.x * 256 + threadIdx.x;
  int i = gtid >> 6;
  int lane = threadIdx.x & 63;
  if (i >= NN) return;
  int s0 = rs[i], s1 = rs[i + 1];
  float acc = G[(size_t)i * HID + lane];  // self-loop term
  int e = s0;
  // 8-wide manual unroll: 8 independent gathers in flight per iteration
  for (; e + 8 <= s1; e += 8) {
    int i0 = csr[e + 0], i1 = csr[e + 1], i2 = csr[e + 2], i3 = csr[e + 3];
    int i4 = csr[e + 4], i5 = csr[e + 5], i6 = csr[e + 6], i7 = csr[e + 7];
    float g0 = G[(size_t)i0 * HID + lane];
    float g1 = G[(size_t)i1 * HID + lane];
    float g2 = G[(size_t)i2 * HID + lane];
    float g3 = G[(size_t)i3 * HID + lane];
    float g4 = G[(size_t)i4 * HID + lane];
    float g5 = G[(size_t)i5 * HID + lane];
    float g6 = G[(size_t)i6 * HID + lane];
    float g7 = G[(size_t)i7 * HID + lane];
    acc += ((g0 + g1) + (g2 + g3)) + ((g4 + g5) + (g6 + g7));
  }
  for (; e < s1; ++e) acc += G[(size_t)csr[e] * HID + lane];

  float val = fmaxf(dis[i] * acc + bias[lane], 0.0f);
  if (!FINAL) {
    Out[(size_t)i * HID + lane] = val;
  } else {
    float r = val * Wout[lane];
#pragma unroll
    for (int off = 32; off > 0; off >>= 1) r += __shfl_down(r, off);
    if (lane == 0) Out[i] = r + bout[0];
  }
}

extern "C" void kernel_launch(void* const* d_in, const int* in_sizes, int n_in,
                              void* d_out, int out_size, void* d_ws, size_t ws_size,
                              hipStream_t stream) {
  const float* x  = (const float*)d_in[0];
  const int*   ei = (const int*)d_in[1];
  const float* W1 = (const float*)d_in[2];
  const float* b1 = (const float*)d_in[3];
  const float* W2 = (const float*)d_in[4];
  const float* b2 = (const float*)d_in[5];
  const float* W3 = (const float*)d_in[6];
  const float* b3 = (const float*)d_in[7];
  const float* Wo = (const float*)d_in[8];
  const float* bo = (const float*)d_in[9];
  float* out = (float*)d_out;

  char* ws = (char*)d_ws;
  size_t o = 0;
  auto alloc = [&](size_t bytes) {
    size_t r = o;
    o = (o + bytes + 255) & ~(size_t)255;
    return r;
  };
  int*   cnt  = (int*)(ws + alloc((size_t)NN * 4));
  int*   fil  = (int*)(ws + alloc((size_t)NN * 4));
  int*   rs   = (int*)(ws + alloc((size_t)(NN + 1) * 4));
  int*   bsum = (int*)(ws + alloc(512 * 4));
  float* dis  = (float*)(ws + alloc((size_t)NN * 4));
  int*   flag = (int*)(ws + alloc(256));
  int*   csr  = (int*)(ws + alloc((size_t)NE * 4));
  float* A    = (float*)(ws + alloc((size_t)NN * HID * 4));
  float* B    = (float*)(ws + alloc((size_t)NN * HID * 4));
  (void)ws_size; (void)in_sizes; (void)n_in; (void)out_size;

  const int NBLK = (NN + 255) / 256;    // 391
  const int EBLK = (NE + 255) / 256;    // 6250
  const int ABLK = (NN * HID) / 256;    // 25000
  const int GBLK = (NN + 127) / 128;    // 782

  zero_kernel<<<NBLK, 256, 0, stream>>>(cnt, fil);
  detect_kernel<<<1, 256, 0, stream>>>(ei, flag);
  hist_kernel<<<EBLK, 256, 0, stream>>>(ei, flag, cnt);
  scan1_kernel<<<NBLK, 256, 0, stream>>>(cnt, rs, bsum);
  scan2_kernel<<<1, 512, 0, stream>>>(bsum, NBLK, rs + NN);
  scan3_kernel<<<NBLK, 256, 0, stream>>>(rs, bsum);
  dis_kernel<<<NBLK, 256, 0, stream>>>(cnt, dis);
  fill_kernel<<<EBLK, 256, 0, stream>>>(ei, flag, rs, fil, csr);

  // Layer 1: in = x (K=128)
  gemm_kernel<128><<<GBLK, 256, 0, stream>>>(x, W1, dis, A);
  agg_kernel<false><<<ABLK, 256, 0, stream>>>(A, rs, csr, dis, b1, nullptr, nullptr, B);
  // Layer 2
  gemm_kernel<64><<<GBLK, 256, 0, stream>>>(B, W2, dis, A);
  agg_kernel<false><<<ABLK, 256, 0, stream>>>(A, rs, csr, dis, b2, nullptr, nullptr, B);
  // Layer 3 + fused readout
  gemm_kernel<64><<<GBLK, 256, 0, stream>>>(B, W3, dis, A);
  agg_kernel<true><<<ABLK, 256, 0, stream>>>(A, rs, csr, dis, b3, Wo, bo, out);
}

// Round 5
// 558.621 us; speedup vs baseline: 1.8144x; 1.0628x over previous
//
#include <hip/hip_runtime.h>

// GCN node regressor: 3x GCNConv(relu) + linear readout, f32.
// N=100000 nodes, E=1600000 edges, IN=128, HID=64.
//
//  - CSR build v2: hist+scan, then two-pass bucketed fill:
//    Pass A: partition edges by dst>>7 into packed ints (dl<<17|s), appended
//            per-bucket (cursors = rs[b*128], padded to 64B to spread atomics).
//            Append streams -> full-line writebacks (vs 102 MB of partial-line
//            scatter writebacks in v1 fill: WRITE_SIZE 107 MB, 118 us).
//    Pass B: one WG per bucket, per-node cursors in LDS; scatter confined to
//            the bucket's ~8 KB csr window -> L2-local, efficient writeback.
//  - GEMM: 128x64 block tile, 8x4 register tile, LDS staged; dis folded in.
//  - agg v2: one wave per node; 4 edges/pass (16-lane group per edge, float4
//    per lane), x2 unrolled; cross-group shfl_xor combine; fused bias+relu;
//    final layer fuses [64]->1 readout.

#define NN 100000
#define NE 1600000
#define HID 64
#define BSH 7                       // 128 nodes per bucket
#define BNODES (1 << BSH)
#define NBUCK ((NN + BNODES - 1) >> BSH)   // 782
#define BCSTRIDE 16                 // pad bucket cursors to 64B

// ---------- edge dtype detection (int32 vs int64 canonicalization) ----------
__global__ __launch_bounds__(256) void detect_kernel(const int* __restrict__ ei,
                                                     int* __restrict__ flag) {
  __shared__ int nz;
  if (threadIdx.x == 0) nz = 0;
  __syncthreads();
  if (ei[2 * threadIdx.x + 1] != 0) atomicAdd(&nz, 1);
  __syncthreads();
  if (threadIdx.x == 0) *flag = (nz == 0) ? 1 : 0;  // 1 => int64 layout
}

__device__ __forceinline__ int load_src(const int* ei, int is64, int e) {
  return is64 ? ei[(size_t)2 * e] : ei[e];
}
__device__ __forceinline__ int load_dst(const int* ei, int is64, int e) {
  return is64 ? ei[(size_t)2 * NE + (size_t)2 * e] : ei[(size_t)NE + e];
}

// ---------- CSR build ----------
__global__ __launch_bounds__(256) void zero_kernel(int* __restrict__ a) {
  int i = blockIdx.x * 256 + threadIdx.x;
  if (i < NN) a[i] = 0;
}

__global__ __launch_bounds__(256) void hist_kernel(const int* __restrict__ ei,
                                                   const int* __restrict__ flag,
                                                   int* __restrict__ cnt) {
  int e = blockIdx.x * 256 + threadIdx.x;
  if (e >= NE) return;
  int is64 = *flag;
  atomicAdd(&cnt[load_dst(ei, is64, e)], 1);
}

__global__ __launch_bounds__(256) void scan1_kernel(const int* __restrict__ cnt,
                                                    int* __restrict__ rs,
                                                    int* __restrict__ bsum) {
  __shared__ int tmp[256];
  int i = blockIdx.x * 256 + threadIdx.x;
  int v = (i < NN) ? cnt[i] : 0;
  int x = v;
  tmp[threadIdx.x] = x;
  __syncthreads();
  for (int off = 1; off < 256; off <<= 1) {
    int y = (threadIdx.x >= off) ? tmp[threadIdx.x - off] : 0;
    __syncthreads();
    x += y;
    tmp[threadIdx.x] = x;
    __syncthreads();
  }
  if (i < NN) rs[i] = x - v;
  if (threadIdx.x == 255) bsum[blockIdx.x] = x;
}

__global__ __launch_bounds__(512) void scan2_kernel(int* __restrict__ bsum, int nb,
                                                    int* __restrict__ total_out) {
  __shared__ int tmp[512];
  int v = (threadIdx.x < nb) ? bsum[threadIdx.x] : 0;
  int x = v;
  tmp[threadIdx.x] = x;
  __syncthreads();
  for (int off = 1; off < 512; off <<= 1) {
    int y = (threadIdx.x >= off) ? tmp[threadIdx.x - off] : 0;
    __syncthreads();
    x += y;
    tmp[threadIdx.x] = x;
    __syncthreads();
  }
  if (threadIdx.x < nb) bsum[threadIdx.x] = x - v;
  if (threadIdx.x == 511) *total_out = x;
}

__global__ __launch_bounds__(256) void scan3_kernel(int* __restrict__ rs,
                                                    const int* __restrict__ bsum) {
  int i = blockIdx.x * 256 + threadIdx.x;
  if (i < NN) rs[i] += bsum[blockIdx.x];
}

__global__ __launch_bounds__(256) void dis_kernel(const int* __restrict__ cnt,
                                                  float* __restrict__ dis) {
  int i = blockIdx.x * 256 + threadIdx.x;
  if (i < NN) dis[i] = rsqrtf((float)cnt[i] + 1.0f);
}

__global__ __launch_bounds__(256) void init_bcur_kernel(const int* __restrict__ rs,
                                                        int* __restrict__ bcur) {
  int b = blockIdx.x * 256 + threadIdx.x;
  if (b < NBUCK) bcur[b * BCSTRIDE] = rs[b << BSH];
}

// Pass A: partition edges into buckets of 128 dst nodes; packed (dl<<17)|s.
__global__ __launch_bounds__(256) void partA_kernel(const int* __restrict__ ei,
                                                    const int* __restrict__ flag,
                                                    int* __restrict__ bcur,
                                                    int* __restrict__ tmp) {
  int e = blockIdx.x * 256 + threadIdx.x;
  if (e >= NE) return;
  int is64 = *flag;
  int s = load_src(ei, is64, e);
  int d = load_dst(ei, is64, e);
  int b = d >> BSH;
  int pos = atomicAdd(&bcur[b * BCSTRIDE], 1);
  tmp[pos] = ((d & (BNODES - 1)) << 17) | s;   // s < 2^17
}

// Pass B: one WG per bucket; LDS per-node cursors; scatter into ~8KB window.
__global__ __launch_bounds__(256) void partB_kernel(const int* __restrict__ rs,
                                                    const int* __restrict__ tmp,
                                                    int* __restrict__ csr) {
  __shared__ int cur[BNODES];
  int b = blockIdx.x;
  int nbase = b << BSH;
  int nend = nbase + BNODES; if (nend > NN) nend = NN;
  int t = threadIdx.x;
  if (t < BNODES) {
    int n = nbase + t;
    cur[t] = (n < NN) ? rs[n] : 0;
  }
  __syncthreads();
  int base = rs[nbase];
  int end = rs[nend];
  for (int e = base + t; e < end; e += 256) {
    int p = tmp[e];
    int s = p & 0x1FFFF;
    int dl = p >> 17;
    int pos = atomicAdd(&cur[dl], 1);
    csr[pos] = s;
  }
}

// ---------- GEMM: G[r][c] = dis[r] * sum_k X[r][k] * W[k][c] ----------
#define KT 32
#define PADX 2
#define PADW 4

template <int K>
__global__ __launch_bounds__(256) void gemm_kernel(const float* __restrict__ X,
                                                   const float* __restrict__ W,
                                                   const float* __restrict__ dis,
                                                   float* __restrict__ G) {
  __shared__ float XsT[KT][128 + PADX];
  __shared__ float Ws[KT][64 + PADW];
  const int t = threadIdx.x;
  const int row0 = blockIdx.x * 128;
  const int r0 = (t & 15) * 8;
  const int c0 = (t >> 4) * 4;

  float acc[8][4];
#pragma unroll
  for (int i = 0; i < 8; ++i)
#pragma unroll
    for (int j = 0; j < 4; ++j) acc[i][j] = 0.f;

  for (int k0 = 0; k0 < K; k0 += KT) {
    __syncthreads();
    {
#pragma unroll
      for (int it = 0; it < 4; ++it) {
        int idx = it * 256 + t;
        int r = idx >> 3;
        int kq = (idx & 7) << 2;
        int rr = row0 + r;
        if (rr >= NN) rr = NN - 1;
        float4 v = *reinterpret_cast<const float4*>(X + (size_t)rr * K + k0 + kq);
        XsT[kq + 0][r] = v.x;
        XsT[kq + 1][r] = v.y;
        XsT[kq + 2][r] = v.z;
        XsT[kq + 3][r] = v.w;
      }
    }
    {
#pragma unroll
      for (int it = 0; it < 2; ++it) {
        int idx = it * 256 + t;
        int kk = idx >> 4;
        int c4 = (idx & 15) << 2;
        float4 v = *reinterpret_cast<const float4*>(W + (size_t)(k0 + kk) * 64 + c4);
        *reinterpret_cast<float4*>(&Ws[kk][c4]) = v;
      }
    }
    __syncthreads();

#pragma unroll 4
    for (int kk = 0; kk < KT; ++kk) {
      float4 w4 = *reinterpret_cast<const float4*>(&Ws[kk][c0]);
      float4 xa = *reinterpret_cast<const float4*>(&XsT[kk][r0]);
      float4 xb = *reinterpret_cast<const float4*>(&XsT[kk][r0 + 4]);
      float xr[8] = {xa.x, xa.y, xa.z, xa.w, xb.x, xb.y, xb.z, xb.w};
      float wr[4] = {w4.x, w4.y, w4.z, w4.w};
#pragma unroll
      for (int i = 0; i < 8; ++i)
#pragma unroll
        for (int j = 0; j < 4; ++j) acc[i][j] = fmaf(xr[i], wr[j], acc[i][j]);
    }
  }

#pragma unroll
  for (int i = 0; i < 8; ++i) {
    int r = row0 + r0 + i;
    if (r < NN) {
      float d = dis[r];
      float4 ov = make_float4(acc[i][0] * d, acc[i][1] * d, acc[i][2] * d, acc[i][3] * d);
      *reinterpret_cast<float4*>(G + (size_t)r * HID + c0) = ov;
    }
  }
}

// ---------- aggregation v2: one wave per node, 4 edges per pass ----------
// lane = (g,q): group g in [0,4) handles edge e+g; lane loads float4 of
// channels [4q,4q+4). Cross-group combine via shfl_xor(16|32).
// out[i][:] = relu(dis[i]*(G[i][:] + sum_e G[csr[e]][:]) + b)
template <bool FINAL>
__global__ __launch_bounds__(256) void agg_kernel(const float* __restrict__ G,
                                                  const int* __restrict__ rs,
                                                  const int* __restrict__ csr,
                                                  const float* __restrict__ dis,
                                                  const float* __restrict__ bias,
                                                  const float* __restrict__ Wout,
                                                  const float* __restrict__ bout,
                                                  float* __restrict__ Out) {
  int gtid = blockIdx.x * 256 + threadIdx.x;
  int i = gtid >> 6;
  if (i >= NN) return;
  int lane = threadIdx.x & 63;
  int g = lane >> 4, q = lane & 15;
  const float4* G4 = reinterpret_cast<const float4*>(G);
  int s0 = rs[i], s1 = rs[i + 1];

  float4 acc = make_float4(0.f, 0.f, 0.f, 0.f);
  if (g == 0) acc = G4[(size_t)i * 16 + q];  // self-loop term, counted once
  int e = s0;
  for (; e + 8 <= s1; e += 8) {
    int sA = csr[e + g];
    int sB = csr[e + 4 + g];
    float4 va = G4[(size_t)sA * 16 + q];
    float4 vb = G4[(size_t)sB * 16 + q];
    acc.x += va.x; acc.y += va.y; acc.z += va.z; acc.w += va.w;
    acc.x += vb.x; acc.y += vb.y; acc.z += vb.z; acc.w += vb.w;
  }
  for (; e < s1; e += 4) {
    int ee = e + g;
    if (ee < s1) {
      float4 v = G4[(size_t)csr[ee] * 16 + q];
      acc.x += v.x; acc.y += v.y; acc.z += v.z; acc.w += v.w;
    }
  }
  // combine the 4 groups' partials (each lane ends with full sum for its q)
  acc.x += __shfl_xor(acc.x, 16); acc.y += __shfl_xor(acc.y, 16);
  acc.z += __shfl_xor(acc.z, 16); acc.w += __shfl_xor(acc.w, 16);
  acc.x += __shfl_xor(acc.x, 32); acc.y += __shfl_xor(acc.y, 32);
  acc.z += __shfl_xor(acc.z, 32); acc.w += __shfl_xor(acc.w, 32);

  float di = dis[i];
  float4 b4 = reinterpret_cast<const float4*>(bias)[q];
  float4 val;
  val.x = fmaxf(fmaf(di, acc.x, b4.x), 0.f);
  val.y = fmaxf(fmaf(di, acc.y, b4.y), 0.f);
  val.z = fmaxf(fmaf(di, acc.z, b4.z), 0.f);
  val.w = fmaxf(fmaf(di, acc.w, b4.w), 0.f);

  if (!FINAL) {
    if (g == 0) reinterpret_cast<float4*>(Out)[(size_t)i * 16 + q] = val;
  } else {
    float4 w4 = reinterpret_cast<const float4*>(Wout)[q];
    float r = val.x * w4.x + val.y * w4.y + val.z * w4.z + val.w * w4.w;
    r += __shfl_xor(r, 1); r += __shfl_xor(r, 2);
    r += __shfl_xor(r, 4); r += __shfl_xor(r, 8);
    if (lane == 0) Out[i] = r + bout[0];
  }
}

extern "C" void kernel_launch(void* const* d_in, const int* in_sizes, int n_in,
                              void* d_out, int out_size, void* d_ws, size_t ws_size,
                              hipStream_t stream) {
  const float* x  = (const float*)d_in[0];
  const int*   ei = (const int*)d_in[1];
  const float* W1 = (const float*)d_in[2];
  const float* b1 = (const float*)d_in[3];
  const float* W2 = (const float*)d_in[4];
  const float* b2 = (const float*)d_in[5];
  const float* W3 = (const float*)d_in[6];
  const float* b3 = (const float*)d_in[7];
  const float* Wo = (const float*)d_in[8];
  const float* bo = (const float*)d_in[9];
  float* out = (float*)d_out;

  char* ws = (char*)d_ws;
  size_t o = 0;
  auto alloc = [&](size_t bytes) {
    size_t r = o;
    o = (o + bytes + 255) & ~(size_t)255;
    return r;
  };
  int*   cnt  = (int*)(ws + alloc((size_t)NN * 4));
  int*   rs   = (int*)(ws + alloc((size_t)(NN + 1) * 4));
  int*   bsum = (int*)(ws + alloc(512 * 4));
  float* dis  = (float*)(ws + alloc((size_t)NN * 4));
  int*   flag = (int*)(ws + alloc(256));
  int*   bcur = (int*)(ws + alloc((size_t)NBUCK * BCSTRIDE * 4));
  int*   csr  = (int*)(ws + alloc((size_t)NE * 4));
  float* A    = (float*)(ws + alloc((size_t)NN * HID * 4));
  float* B    = (float*)(ws + alloc((size_t)NN * HID * 4));
  int*   tmp  = (int*)B;  // aliases B: only live before layer-1 agg writes B
  (void)ws_size; (void)in_sizes; (void)n_in; (void)out_size;

  const int NBLK = (NN + 255) / 256;    // 391
  const int EBLK = (NE + 255) / 256;    // 6250
  const int ABLK = (NN * HID) / 256;    // 25000
  const int GBLK = (NN + 127) / 128;    // 782

  zero_kernel<<<NBLK, 256, 0, stream>>>(cnt);
  detect_kernel<<<1, 256, 0, stream>>>(ei, flag);
  hist_kernel<<<EBLK, 256, 0, stream>>>(ei, flag, cnt);
  scan1_kernel<<<NBLK, 256, 0, stream>>>(cnt, rs, bsum);
  scan2_kernel<<<1, 512, 0, stream>>>(bsum, NBLK, rs + NN);
  scan3_kernel<<<NBLK, 256, 0, stream>>>(rs, bsum);
  dis_kernel<<<NBLK, 256, 0, stream>>>(cnt, dis);
  init_bcur_kernel<<<(NBUCK + 255) / 256, 256, 0, stream>>>(rs, bcur);
  partA_kernel<<<EBLK, 256, 0, stream>>>(ei, flag, bcur, tmp);
  partB_kernel<<<NBUCK, 256, 0, stream>>>(rs, tmp, csr);

  // Layer 1: in = x (K=128)
  gemm_kernel<128><<<GBLK, 256, 0, stream>>>(x, W1, dis, A);
  agg_kernel<false><<<ABLK, 256, 0, stream>>>(A, rs, csr, dis, b1, nullptr, nullptr, B);
  // Layer 2
  gemm_kernel<64><<<GBLK, 256, 0, stream>>>(B, W2, dis, A);
  agg_kernel<false><<<ABLK, 256, 0, stream>>>(A, rs, csr, dis, b2, nullptr, nullptr, B);
  // Layer 3 + fused readout
  gemm_kernel<64><<<GBLK, 256, 0, stream>>>(B, W3, dis, A);
  agg_kernel<true><<<ABLK, 256, 0, stream>>>(A, rs, csr, dis, b3, Wo, bo, out);
}

// Round 7
// 447.696 us; speedup vs baseline: 2.2639x; 1.2478x over previous
//
#include <hip/hip_runtime.h>

// GCN node regressor: 3x GCNConv(relu) + linear readout, f32.
// N=100000 nodes, E=1600000 edges, IN=128, HID=64.
//
// CSR build v3 (fixes partA write-amplification: 81 MB -> ~8 MB):
//   bhist: coarse bucket (dst>>9, 196 buckets) histogram, LDS-privatized.
//   bscan: 1-WG scan -> bstart[197]; seeds padded global bucket cursors.
//   partA: per-WG counting sort. Each WG register-caches 3328 edges,
//          LDS-histograms them, reserves contiguous global slots per bucket
//          (one atomicAdd per bucket per WG), reorders via LDS staging, and
//          copies out contiguous runs -> full-line writebacks.
//   partB: one WG per bucket; per-node counts + scan in LDS -> writes rs/dis
//          directly (replaces global hist/scan/dis kernels); then scatters
//          csr within the bucket's ~32KB L2-resident window.
// GEMM: 128x64 block tile, 8x4 register tile, LDS staged; dis folded in.
// agg: one wave per node; 4 edges/pass (16-lane group per edge, float4 per
//      lane); cross-group shfl_xor combine; fused bias+relu; final layer
//      fuses the [64]->1 readout.

#define NN 100000
#define NE 1600000
#define HID 64
#define BSH 9                        // 512 nodes per bucket
#define BNODES (1 << BSH)
#define NBUCK ((NN + BNODES - 1) >> BSH)   // 196
#define BCSTRIDE 16                  // pad bucket cursors to 64B
#define EPT 13                       // edges per thread in partA
#define EW (EPT * 256)               // 3328 edges per WG
#define NWGA ((NE + EW - 1) / EW)    // 481

// ---------- edge dtype detection (int32 vs int64 canonicalization) ----------
__global__ __launch_bounds__(256) void detect_kernel(const int* __restrict__ ei,
                                                     int* __restrict__ flag) {
  __shared__ int nz;
  if (threadIdx.x == 0) nz = 0;
  __syncthreads();
  if (ei[2 * threadIdx.x + 1] != 0) atomicAdd(&nz, 1);
  __syncthreads();
  if (threadIdx.x == 0) *flag = (nz == 0) ? 1 : 0;  // 1 => int64 layout
}

__device__ __forceinline__ int load_src(const int* ei, int is64, int e) {
  return is64 ? ei[(size_t)2 * e] : ei[e];
}
__device__ __forceinline__ int load_dst(const int* ei, int is64, int e) {
  return is64 ? ei[(size_t)2 * NE + (size_t)2 * e] : ei[(size_t)NE + e];
}

// ---------- coarse bucket histogram ----------
__global__ __launch_bounds__(256) void zerob_kernel(int* __restrict__ gbcnt) {
  if (blockIdx.x == 0 && threadIdx.x < NBUCK) gbcnt[threadIdx.x] = 0;
}

__global__ __launch_bounds__(256) void bhist_kernel(const int* __restrict__ ei,
                                                    const int* __restrict__ flag,
                                                    int* __restrict__ gbcnt) {
  __shared__ int lh[256];
  int t = threadIdx.x;
  lh[t] = 0;
  __syncthreads();
  int is64 = *flag;
  for (int e = blockIdx.x * 256 + t; e < NE; e += gridDim.x * 256) {
    int d = load_dst(ei, is64, e);
    atomicAdd(&lh[d >> BSH], 1);
  }
  __syncthreads();
  if (t < NBUCK && lh[t]) atomicAdd(&gbcnt[t], lh[t]);
}

// 1 WG: exclusive scan of 196 bucket counts -> bstart; seed cursors; rs[NN].
__global__ __launch_bounds__(256) void bscan_kernel(const int* __restrict__ gbcnt,
                                                    int* __restrict__ bstart,
                                                    int* __restrict__ bcur,
                                                    int* __restrict__ rs) {
  __shared__ int sc[256];
  int t = threadIdx.x;
  int v = (t < NBUCK) ? gbcnt[t] : 0;
  sc[t] = v;
  __syncthreads();
  for (int off = 1; off < 256; off <<= 1) {
    int y = (t >= off) ? sc[t - off] : 0;
    __syncthreads();
    sc[t] += y;
    __syncthreads();
  }
  int excl = sc[t] - v;
  if (t < NBUCK) {
    bstart[t] = excl;
    bcur[t * BCSTRIDE] = excl;
  }
  if (t == 0) {
    bstart[NBUCK] = NE;
    rs[NN] = NE;
  }
}

// ---------- partA: per-WG counting sort into bucket-contiguous tmp ----------
// tmp entry: (dl << 17) | s, dl = d & 511 (9b), s < 2^17.
__global__ __launch_bounds__(256) void partA_kernel(const int* __restrict__ ei,
                                                    const int* __restrict__ flag,
                                                    int* __restrict__ bcur,
                                                    int* __restrict__ tmp) {
  __shared__ int lcnt[256];
  __shared__ int sc[256];
  __shared__ int gpos[256];
  __shared__ int stage[EW];
  const int t = threadIdx.x;
  const int base = blockIdx.x * EW;
  const int is64 = *flag;

  // register-cache this WG's edges
  int dreg[EPT], sreg[EPT];
#pragma unroll
  for (int u = 0; u < EPT; ++u) {
    int e = base + u * 256 + t;
    int ok = e < NE;
    int ec = ok ? e : (NE - 1);
    dreg[u] = load_dst(ei, is64, ec);
    sreg[u] = load_src(ei, is64, ec);
    if (!ok) dreg[u] = -1;  // invalid marker
  }

  lcnt[t] = 0;
  __syncthreads();
#pragma unroll
  for (int u = 0; u < EPT; ++u)
    if (dreg[u] >= 0) atomicAdd(&lcnt[dreg[u] >> BSH], 1);
  __syncthreads();

  // inclusive scan of lcnt -> sc
  sc[t] = lcnt[t];
  __syncthreads();
  for (int off = 1; off < 256; off <<= 1) {
    int y = (t >= off) ? sc[t - off] : 0;
    __syncthreads();
    sc[t] += y;
    __syncthreads();
  }
  // reserve contiguous global slots for each non-empty bucket
  if (t < NBUCK && lcnt[t] > 0)
    gpos[t] = atomicAdd(&bcur[t * BCSTRIDE], lcnt[t]);
  // convert sc to exclusive (scatter cursors); final value returns to inclusive
  sc[t] -= lcnt[t];
  __syncthreads();

#pragma unroll
  for (int u = 0; u < EPT; ++u) {
    if (dreg[u] >= 0) {
      int b = dreg[u] >> BSH;
      int p = atomicAdd(&sc[b], 1);
      stage[p] = ((dreg[u] & (BNODES - 1)) << 17) | sreg[u];
    }
  }
  __syncthreads();
  // copy-out: contiguous runs per bucket; binary search bucket of idx
  int total = base + EW <= NE ? EW : (NE - base);
  for (int idx = t; idx < total; idx += 256) {
    int lo = 0, hi = NBUCK - 1;
    while (lo < hi) {
      int mid = (lo + hi) >> 1;
      if (sc[mid] > idx) hi = mid; else lo = mid + 1;
    }
    int b = lo;                      // first bucket with inclusive-end > idx
    int off_b = sc[b] - lcnt[b];     // exclusive start of run
    tmp[gpos[b] + (idx - off_b)] = stage[idx];
  }
}

// ---------- partB: per-bucket node hist/scan -> rs, dis; scatter csr ----------
__global__ __launch_bounds__(256) void partB_kernel(const int* __restrict__ bstart,
                                                    const int* __restrict__ tmp,
                                                    int* __restrict__ rs,
                                                    float* __restrict__ dis,
                                                    int* __restrict__ csr) {
  __shared__ int cnt[BNODES];
  __shared__ int sc[BNODES];
  __shared__ int t2[256];
  const int b = blockIdx.x;
  const int t = threadIdx.x;
  const int nbase = b << BSH;
  const int e0 = bstart[b], e1 = bstart[b + 1];

  cnt[t] = 0; cnt[t + 256] = 0;
  __syncthreads();
  for (int e = e0 + t; e < e1; e += 256)
    atomicAdd(&cnt[tmp[e] >> 17], 1);
  __syncthreads();

  // exclusive scan over 512 node counts (2 per thread)
  int a0 = cnt[2 * t], a1 = cnt[2 * t + 1];
  t2[t] = a0 + a1;
  __syncthreads();
  for (int off = 1; off < 256; off <<= 1) {
    int y = (t >= off) ? t2[t - off] : 0;
    __syncthreads();
    t2[t] += y;
    __syncthreads();
  }
  int pbase = t2[t] - (a0 + a1);
  sc[2 * t] = pbase;
  sc[2 * t + 1] = pbase + a0;
  __syncthreads();

  // emit rs/dis; convert sc to absolute scatter cursors
#pragma unroll
  for (int rep = 0; rep < 2; ++rep) {
    int j = t + rep * 256;
    int n = nbase + j;
    if (n < NN) {
      rs[n] = e0 + sc[j];
      dis[n] = rsqrtf((float)cnt[j] + 1.0f);
    }
    sc[j] += e0;
  }
  __syncthreads();

  for (int e = e0 + t; e < e1; e += 256) {
    int p = tmp[e];
    int pos = atomicAdd(&sc[p >> 17], 1);
    csr[pos] = p & 0x1FFFF;
  }
}

// ---------- GEMM: G[r][c] = dis[r] * sum_k X[r][k] * W[k][c] ----------
#define KT 32
#define PADX 2
#define PADW 4

template <int K>
__global__ __launch_bounds__(256) void gemm_kernel(const float* __restrict__ X,
                                                   const float* __restrict__ W,
                                                   const float* __restrict__ dis,
                                                   float* __restrict__ G) {
  __shared__ float XsT[KT][128 + PADX];
  __shared__ float Ws[KT][64 + PADW];
  const int t = threadIdx.x;
  const int row0 = blockIdx.x * 128;
  const int r0 = (t & 15) * 8;
  const int c0 = (t >> 4) * 4;

  float acc[8][4];
#pragma unroll
  for (int i = 0; i < 8; ++i)
#pragma unroll
    for (int j = 0; j < 4; ++j) acc[i][j] = 0.f;

  for (int k0 = 0; k0 < K; k0 += KT) {
    __syncthreads();
    {
#pragma unroll
      for (int it = 0; it < 4; ++it) {
        int idx = it * 256 + t;
        int r = idx >> 3;
        int kq = (idx & 7) << 2;
        int rr = row0 + r;
        if (rr >= NN) rr = NN - 1;
        float4 v = *reinterpret_cast<const float4*>(X + (size_t)rr * K + k0 + kq);
        XsT[kq + 0][r] = v.x;
        XsT[kq + 1][r] = v.y;
        XsT[kq + 2][r] = v.z;
        XsT[kq + 3][r] = v.w;
      }
    }
    {
#pragma unroll
      for (int it = 0; it < 2; ++it) {
        int idx = it * 256 + t;
        int kk = idx >> 4;
        int c4 = (idx & 15) << 2;
        float4 v = *reinterpret_cast<const float4*>(W + (size_t)(k0 + kk) * 64 + c4);
        *reinterpret_cast<float4*>(&Ws[kk][c4]) = v;
      }
    }
    __syncthreads();

#pragma unroll 4
    for (int kk = 0; kk < KT; ++kk) {
      float4 w4 = *reinterpret_cast<const float4*>(&Ws[kk][c0]);
      float4 xa = *reinterpret_cast<const float4*>(&XsT[kk][r0]);
      float4 xb = *reinterpret_cast<const float4*>(&XsT[kk][r0 + 4]);
      float xr[8] = {xa.x, xa.y, xa.z, xa.w, xb.x, xb.y, xb.z, xb.w};
      float wr[4] = {w4.x, w4.y, w4.z, w4.w};
#pragma unroll
      for (int i = 0; i < 8; ++i)
#pragma unroll
        for (int j = 0; j < 4; ++j) acc[i][j] = fmaf(xr[i], wr[j], acc[i][j]);
    }
  }

#pragma unroll
  for (int i = 0; i < 8; ++i) {
    int r = row0 + r0 + i;
    if (r < NN) {
      float d = dis[r];
      float4 ov = make_float4(acc[i][0] * d, acc[i][1] * d, acc[i][2] * d, acc[i][3] * d);
      *reinterpret_cast<float4*>(G + (size_t)r * HID + c0) = ov;
    }
  }
}

// ---------- aggregation: one wave per node, 4 edges per pass ----------
template <bool FINAL>
__global__ __launch_bounds__(256) void agg_kernel(const float* __restrict__ G,
                                                  const int* __restrict__ rs,
                                                  const int* __restrict__ csr,
                                                  const float* __restrict__ dis,
                                                  const float* __restrict__ bias,
                                                  const float* __restrict__ Wout,
                                                  const float* __restrict__ bout,
                                                  float* __restrict__ Out) {
  int gtid = blockIdx.x * 256 + threadIdx.x;
  int i = gtid >> 6;
  if (i >= NN) return;
  int lane = threadIdx.x & 63;
  int g = lane >> 4, q = lane & 15;
  const float4* G4 = reinterpret_cast<const float4*>(G);
  int s0 = rs[i], s1 = rs[i + 1];

  float4 acc = make_float4(0.f, 0.f, 0.f, 0.f);
  if (g == 0) acc = G4[(size_t)i * 16 + q];  // self-loop term, counted once
  int e = s0;
  for (; e + 8 <= s1; e += 8) {
    int sA = csr[e + g];
    int sB = csr[e + 4 + g];
    float4 va = G4[(size_t)sA * 16 + q];
    float4 vb = G4[(size_t)sB * 16 + q];
    acc.x += va.x; acc.y += va.y; acc.z += va.z; acc.w += va.w;
    acc.x += vb.x; acc.y += vb.y; acc.z += vb.z; acc.w += vb.w;
  }
  for (; e < s1; e += 4) {
    int ee = e + g;
    if (ee < s1) {
      float4 v = G4[(size_t)csr[ee] * 16 + q];
      acc.x += v.x; acc.y += v.y; acc.z += v.z; acc.w += v.w;
    }
  }
  acc.x += __shfl_xor(acc.x, 16); acc.y += __shfl_xor(acc.y, 16);
  acc.z += __shfl_xor(acc.z, 16); acc.w += __shfl_xor(acc.w, 16);
  acc.x += __shfl_xor(acc.x, 32); acc.y += __shfl_xor(acc.y, 32);
  acc.z += __shfl_xor(acc.z, 32); acc.w += __shfl_xor(acc.w, 32);

  float di = dis[i];
  float4 b4 = reinterpret_cast<const float4*>(bias)[q];
  float4 val;
  val.x = fmaxf(fmaf(di, acc.x, b4.x), 0.f);
  val.y = fmaxf(fmaf(di, acc.y, b4.y), 0.f);
  val.z = fmaxf(fmaf(di, acc.z, b4.z), 0.f);
  val.w = fmaxf(fmaf(di, acc.w, b4.w), 0.f);

  if (!FINAL) {
    if (g == 0) reinterpret_cast<float4*>(Out)[(size_t)i * 16 + q] = val;
  } else {
    float4 w4 = reinterpret_cast<const float4*>(Wout)[q];
    float r = val.x * w4.x + val.y * w4.y + val.z * w4.z + val.w * w4.w;
    r += __shfl_xor(r, 1); r += __shfl_xor(r, 2);
    r += __shfl_xor(r, 4); r += __shfl_xor(r, 8);
    if (lane == 0) Out[i] = r + bout[0];
  }
}

extern "C" void kernel_launch(void* const* d_in, const int* in_sizes, int n_in,
                              void* d_out, int out_size, void* d_ws, size_t ws_size,
                              hipStream_t stream) {
  const float* x  = (const float*)d_in[0];
  const int*   ei = (const int*)d_in[1];
  const float* W1 = (const float*)d_in[2];
  const float* b1 = (const float*)d_in[3];
  const float* W2 = (const float*)d_in[4];
  const float* b2 = (const float*)d_in[5];
  const float* W3 = (const float*)d_in[6];
  const float* b3 = (const float*)d_in[7];
  const float* Wo = (const float*)d_in[8];
  const float* bo = (const float*)d_in[9];
  float* out = (float*)d_out;

  char* ws = (char*)d_ws;
  size_t o = 0;
  auto alloc = [&](size_t bytes) {
    size_t r = o;
    o = (o + bytes + 255) & ~(size_t)255;
    return r;
  };
  int*   rs     = (int*)(ws + alloc((size_t)(NN + 1) * 4));
  float* dis    = (float*)(ws + alloc((size_t)NN * 4));
  int*   flag   = (int*)(ws + alloc(256));
  int*   gbcnt  = (int*)(ws + alloc((size_t)NBUCK * 4));
  int*   bstart = (int*)(ws + alloc((size_t)(NBUCK + 1) * 4));
  int*   bcur   = (int*)(ws + alloc((size_t)NBUCK * BCSTRIDE * 4));
  int*   csr    = (int*)(ws + alloc((size_t)NE * 4));
  float* A      = (float*)(ws + alloc((size_t)NN * HID * 4));
  float* B      = (float*)(ws + alloc((size_t)NN * HID * 4));
  int*   tmp    = (int*)B;  // aliases B: only live before layer-1 agg writes B
  (void)ws_size; (void)in_sizes; (void)n_in; (void)out_size;

  const int ABLK = (NN * HID) / 256;    // 25000
  const int GBLK = (NN + 127) / 128;    // 782

  detect_kernel<<<1, 256, 0, stream>>>(ei, flag);
  zerob_kernel<<<1, 256, 0, stream>>>(gbcnt);
  bhist_kernel<<<400, 256, 0, stream>>>(ei, flag, gbcnt);
  bscan_kernel<<<1, 256, 0, stream>>>(gbcnt, bstart, bcur, rs);
  partA_kernel<<<NWGA, 256, 0, stream>>>(ei, flag, bcur, tmp);
  partB_kernel<<<NBUCK, 256, 0, stream>>>(bstart, tmp, rs, dis, csr);

  // Layer 1: in = x (K=128)
  gemm_kernel<128><<<GBLK, 256, 0, stream>>>(x, W1, dis, A);
  agg_kernel<false><<<ABLK, 256, 0, stream>>>(A, rs, csr, dis, b1, nullptr, nullptr, B);
  // Layer 2
  gemm_kernel<64><<<GBLK, 256, 0, stream>>>(B, W2, dis, A);
  agg_kernel<false><<<ABLK, 256, 0, stream>>>(A, rs, csr, dis, b2, nullptr, nullptr, B);
  // Layer 3 + fused readout
  gemm_kernel<64><<<GBLK, 256, 0, stream>>>(B, W3, dis, A);
  agg_kernel<true><<<ABLK, 256, 0, stream>>>(A, rs, csr, dis, b3, Wo, bo, out);
}

// Round 10
// 413.605 us; speedup vs baseline: 2.4505x; 1.0824x over previous
//
#include <hip/hip_runtime.h>
#include <hip/hip_fp16.h>

// GCN node regressor: 3x GCNConv(relu) + linear readout.
// N=100000 nodes, E=1600000 edges, IN=128, HID=64.
//
// v4: fp16 storage for node-feature matrices A/B (f32 accumulation).
//     agg's random gather is fetch-floor-bound across 8 private XCD L2s
//     (FETCH 190 MB ~ 8x|G|); halving row bytes (256B->128B) is the only
//     remaining lever. fp16 rel-err 2^-12 keeps absmax ~1e-3 << 3.9e-3.
// CSR build v3: bhist -> bscan -> partA (per-WG counting sort, contiguous
//     run copy-out) -> partB (per-bucket LDS node hist/scan -> rs/dis, local
//     scatter). No global float atomics anywhere.
// GEMM: 128x64 tile, 8x4 register tile, LDS staged; dis folded into epilogue;
//     f32 input (layer 1) or fp16 input (layers 2,3); fp16 output.
// agg: one wave per node; 16-lane group per edge row; f32 accumulate; fused
//     bias+relu; final layer fuses the [64]->1 readout in f32.

#define NN 100000
#define NE 1600000
#define HID 64
#define BSH 9                        // 512 nodes per bucket
#define BNODES (1 << BSH)
#define NBUCK ((NN + BNODES - 1) >> BSH)   // 196
#define BCSTRIDE 16                  // pad bucket cursors to 64B
#define EPT 13                       // edges per thread in partA
#define EW (EPT * 256)               // 3328 edges per WG
#define NWGA ((NE + EW - 1) / EW)    // 481

// ---------- edge dtype detection + gbcnt zero ----------
__global__ __launch_bounds__(256) void detect_kernel(const int* __restrict__ ei,
                                                     int* __restrict__ flag,
                                                     int* __restrict__ gbcnt) {
  __shared__ int nz;
  if (threadIdx.x == 0) nz = 0;
  if (threadIdx.x < NBUCK) gbcnt[threadIdx.x] = 0;
  __syncthreads();
  if (ei[2 * threadIdx.x + 1] != 0) atomicAdd(&nz, 1);
  __syncthreads();
  if (threadIdx.x == 0) *flag = (nz == 0) ? 1 : 0;  // 1 => int64 layout
}

__device__ __forceinline__ int load_src(const int* ei, int is64, int e) {
  return is64 ? ei[(size_t)2 * e] : ei[e];
}
__device__ __forceinline__ int load_dst(const int* ei, int is64, int e) {
  return is64 ? ei[(size_t)2 * NE + (size_t)2 * e] : ei[(size_t)NE + e];
}

// ---------- coarse bucket histogram ----------
__global__ __launch_bounds__(256) void bhist_kernel(const int* __restrict__ ei,
                                                    const int* __restrict__ flag,
                                                    int* __restrict__ gbcnt) {
  __shared__ int lh[256];
  int t = threadIdx.x;
  lh[t] = 0;
  __syncthreads();
  int is64 = *flag;
  for (int e = blockIdx.x * 256 + t; e < NE; e += gridDim.x * 256) {
    int d = load_dst(ei, is64, e);
    atomicAdd(&lh[d >> BSH], 1);
  }
  __syncthreads();
  if (t < NBUCK && lh[t]) atomicAdd(&gbcnt[t], lh[t]);
}

// 1 WG: exclusive scan of 196 bucket counts -> bstart; seed cursors; rs[NN].
__global__ __launch_bounds__(256) void bscan_kernel(const int* __restrict__ gbcnt,
                                                    int* __restrict__ bstart,
                                                    int* __restrict__ bcur,
                                                    int* __restrict__ rs) {
  __shared__ int sc[256];
  int t = threadIdx.x;
  int v = (t < NBUCK) ? gbcnt[t] : 0;
  sc[t] = v;
  __syncthreads();
  for (int off = 1; off < 256; off <<= 1) {
    int y = (t >= off) ? sc[t - off] : 0;
    __syncthreads();
    sc[t] += y;
    __syncthreads();
  }
  int excl = sc[t] - v;
  if (t < NBUCK) {
    bstart[t] = excl;
    bcur[t * BCSTRIDE] = excl;
  }
  if (t == 0) {
    bstart[NBUCK] = NE;
    rs[NN] = NE;
  }
}

// ---------- partA: per-WG counting sort into bucket-contiguous tmp ----------
// tmp entry: (dl << 17) | s, dl = d & 511 (9b), s < 2^17.
__global__ __launch_bounds__(256) void partA_kernel(const int* __restrict__ ei,
                                                    const int* __restrict__ flag,
                                                    int* __restrict__ bcur,
                                                    int* __restrict__ tmp) {
  __shared__ int lcnt[256];
  __shared__ int sc[256];
  __shared__ int gpos[256];
  __shared__ int stage[EW];
  const int t = threadIdx.x;
  const int base = blockIdx.x * EW;
  const int is64 = *flag;

  int dreg[EPT], sreg[EPT];
#pragma unroll
  for (int u = 0; u < EPT; ++u) {
    int e = base + u * 256 + t;
    int ok = e < NE;
    int ec = ok ? e : (NE - 1);
    dreg[u] = load_dst(ei, is64, ec);
    sreg[u] = load_src(ei, is64, ec);
    if (!ok) dreg[u] = -1;
  }

  lcnt[t] = 0;
  __syncthreads();
#pragma unroll
  for (int u = 0; u < EPT; ++u)
    if (dreg[u] >= 0) atomicAdd(&lcnt[dreg[u] >> BSH], 1);
  __syncthreads();

  sc[t] = lcnt[t];
  __syncthreads();
  for (int off = 1; off < 256; off <<= 1) {
    int y = (t >= off) ? sc[t - off] : 0;
    __syncthreads();
    sc[t] += y;
    __syncthreads();
  }
  if (t < NBUCK && lcnt[t] > 0)
    gpos[t] = atomicAdd(&bcur[t * BCSTRIDE], lcnt[t]);
  sc[t] -= lcnt[t];
  __syncthreads();

#pragma unroll
  for (int u = 0; u < EPT; ++u) {
    if (dreg[u] >= 0) {
      int b = dreg[u] >> BSH;
      int p = atomicAdd(&sc[b], 1);
      stage[p] = ((dreg[u] & (BNODES - 1)) << 17) | sreg[u];
    }
  }
  __syncthreads();
  int total = base + EW <= NE ? EW : (NE - base);
  for (int idx = t; idx < total; idx += 256) {
    int lo = 0, hi = NBUCK - 1;
    while (lo < hi) {
      int mid = (lo + hi) >> 1;
      if (sc[mid] > idx) hi = mid; else lo = mid + 1;
    }
    int b = lo;
    int off_b = sc[b] - lcnt[b];
    tmp[gpos[b] + (idx - off_b)] = stage[idx];
  }
}

// ---------- partB: per-bucket node hist/scan -> rs, dis; scatter csr ----------
__global__ __launch_bounds__(256) void partB_kernel(const int* __restrict__ bstart,
                                                    const int* __restrict__ tmp,
                                                    int* __restrict__ rs,
                                                    float* __restrict__ dis,
                                                    int* __restrict__ csr) {
  __shared__ int cnt[BNODES];
  __shared__ int sc[BNODES];
  __shared__ int t2[256];
  const int b = blockIdx.x;
  const int t = threadIdx.x;
  const int nbase = b << BSH;
  const int e0 = bstart[b], e1 = bstart[b + 1];

  cnt[t] = 0; cnt[t + 256] = 0;
  __syncthreads();
  for (int e = e0 + t; e < e1; e += 256)
    atomicAdd(&cnt[tmp[e] >> 17], 1);
  __syncthreads();

  int a0 = cnt[2 * t], a1 = cnt[2 * t + 1];
  t2[t] = a0 + a1;
  __syncthreads();
  for (int off = 1; off < 256; off <<= 1) {
    int y = (t >= off) ? t2[t - off] : 0;
    __syncthreads();
    t2[t] += y;
    __syncthreads();
  }
  int pbase = t2[t] - (a0 + a1);
  sc[2 * t] = pbase;
  sc[2 * t + 1] = pbase + a0;
  __syncthreads();

#pragma unroll
  for (int rep = 0; rep < 2; ++rep) {
    int j = t + rep * 256;
    int n = nbase + j;
    if (n < NN) {
      rs[n] = e0 + sc[j];
      dis[n] = rsqrtf((float)cnt[j] + 1.0f);
    }
    sc[j] += e0;
  }
  __syncthreads();

  for (int e = e0 + t; e < e1; e += 256) {
    int p = tmp[e];
    int pos = atomicAdd(&sc[p >> 17], 1);
    csr[pos] = p & 0x1FFFF;
  }
}

// ---------- GEMM: G[r][c] = fp16( dis[r] * sum_k X[r][k] * W[k][c] ) ----------
#define KT 32
#define PADX 2
#define PADW 4

template <int K, bool HALF_IN>
__global__ __launch_bounds__(256) void gemm_kernel(const void* __restrict__ Xv,
                                                   const float* __restrict__ W,
                                                   const float* __restrict__ dis,
                                                   __half* __restrict__ G) {
  __shared__ float XsT[KT][128 + PADX];
  __shared__ float Ws[KT][64 + PADW];
  const int t = threadIdx.x;
  const int row0 = blockIdx.x * 128;
  const int r0 = (t & 15) * 8;
  const int c0 = (t >> 4) * 4;

  float acc[8][4];
#pragma unroll
  for (int i = 0; i < 8; ++i)
#pragma unroll
    for (int j = 0; j < 4; ++j) acc[i][j] = 0.f;

  for (int k0 = 0; k0 < K; k0 += KT) {
    __syncthreads();
    if constexpr (!HALF_IN) {
      const float* X = (const float*)Xv;
#pragma unroll
      for (int it = 0; it < 4; ++it) {
        int idx = it * 256 + t;          // 0..1023
        int r = idx >> 3;                // 0..127
        int kq = (idx & 7) << 2;         // 0..28
        int rr = row0 + r;
        if (rr >= NN) rr = NN - 1;
        float4 v = *reinterpret_cast<const float4*>(X + (size_t)rr * K + k0 + kq);
        XsT[kq + 0][r] = v.x;
        XsT[kq + 1][r] = v.y;
        XsT[kq + 2][r] = v.z;
        XsT[kq + 3][r] = v.w;
      }
    } else {
      const __half* X = (const __half*)Xv;
#pragma unroll
      for (int it = 0; it < 2; ++it) {
        int idx = it * 256 + t;          // 0..511
        int r = idx >> 2;                // 0..127
        int ko = (idx & 3) << 3;         // 0,8,16,24
        int rr = row0 + r;
        if (rr >= NN) rr = NN - 1;
        float4 raw = *reinterpret_cast<const float4*>(X + (size_t)rr * K + k0 + ko);
        const __half2* hp = reinterpret_cast<const __half2*>(&raw);
#pragma unroll
        for (int j = 0; j < 4; ++j) {
          float2 f = __half22float2(hp[j]);
          XsT[ko + 2 * j + 0][r] = f.x;
          XsT[ko + 2 * j + 1][r] = f.y;
        }
      }
    }
    {
#pragma unroll
      for (int it = 0; it < 2; ++it) {
        int idx = it * 256 + t;
        int kk = idx >> 4;
        int c4 = (idx & 15) << 2;
        float4 v = *reinterpret_cast<const float4*>(W + (size_t)(k0 + kk) * 64 + c4);
        *reinterpret_cast<float4*>(&Ws[kk][c4]) = v;
      }
    }
    __syncthreads();

#pragma unroll 4
    for (int kk = 0; kk < KT; ++kk) {
      float4 w4 = *reinterpret_cast<const float4*>(&Ws[kk][c0]);
      float4 xa = *reinterpret_cast<const float4*>(&XsT[kk][r0]);
      float4 xb = *reinterpret_cast<const float4*>(&XsT[kk][r0 + 4]);
      float xr[8] = {xa.x, xa.y, xa.z, xa.w, xb.x, xb.y, xb.z, xb.w};
      float wr[4] = {w4.x, w4.y, w4.z, w4.w};
#pragma unroll
      for (int i = 0; i < 8; ++i)
#pragma unroll
        for (int j = 0; j < 4; ++j) acc[i][j] = fmaf(xr[i], wr[j], acc[i][j]);
    }
  }

#pragma unroll
  for (int i = 0; i < 8; ++i) {
    int r = row0 + r0 + i;
    if (r < NN) {
      float d = dis[r];
      __half2 p0 = __floats2half2_rn(acc[i][0] * d, acc[i][1] * d);
      __half2 p1 = __floats2half2_rn(acc[i][2] * d, acc[i][3] * d);
      __half2 pr[2] = {p0, p1};
      *reinterpret_cast<float2*>(G + (size_t)r * HID + c0) =
          *reinterpret_cast<float2*>(pr);
    }
  }
}

// ---------- aggregation: one wave per node, 4 edges per pass, fp16 rows ----------
// lane = (g,q): group g in [0,4) handles edge e+g; lane q loads 4 halves
// (8 B) of channels [4q,4q+4). f32 accumulate; cross-group shfl_xor combine.
template <bool FINAL>
__global__ __launch_bounds__(256) void agg_kernel(const __half* __restrict__ G,
                                                  const int* __restrict__ rs,
                                                  const int* __restrict__ csr,
                                                  const float* __restrict__ dis,
                                                  const float* __restrict__ bias,
                                                  const float* __restrict__ Wout,
                                                  const float* __restrict__ bout,
                                                  __half* __restrict__ OutH,
                                                  float* __restrict__ OutF) {
  int gtid = blockIdx.x * 256 + threadIdx.x;
  int i = gtid >> 6;
  if (i >= NN) return;
  int lane = threadIdx.x & 63;
  int g = lane >> 4, q = lane & 15;
  const float2* G2 = reinterpret_cast<const float2*>(G);  // 16 float2 per row
  int s0 = rs[i], s1 = rs[i + 1];

  float4 acc = make_float4(0.f, 0.f, 0.f, 0.f);
  auto addrow = [&](int src) {
    float2 raw = G2[(size_t)src * 16 + q];
    const __half2* hp = reinterpret_cast<const __half2*>(&raw);
    float2 a = __half22float2(hp[0]);
    float2 b = __half22float2(hp[1]);
    acc.x += a.x; acc.y += a.y; acc.z += b.x; acc.w += b.y;
  };
  if (g == 0) addrow(i);  // self-loop term, counted once
  int e = s0;
  for (; e + 8 <= s1; e += 8) {
    int sA = csr[e + g];
    int sB = csr[e + 4 + g];
    addrow(sA);
    addrow(sB);
  }
  for (; e < s1; e += 4) {
    int ee = e + g;
    if (ee < s1) addrow(csr[ee]);
  }
  acc.x += __shfl_xor(acc.x, 16); acc.y += __shfl_xor(acc.y, 16);
  acc.z += __shfl_xor(acc.z, 16); acc.w += __shfl_xor(acc.w, 16);
  acc.x += __shfl_xor(acc.x, 32); acc.y += __shfl_xor(acc.y, 32);
  acc.z += __shfl_xor(acc.z, 32); acc.w += __shfl_xor(acc.w, 32);

  float di = dis[i];
  float4 b4 = reinterpret_cast<const float4*>(bias)[q];
  float4 val;
  val.x = fmaxf(fmaf(di, acc.x, b4.x), 0.f);
  val.y = fmaxf(fmaf(di, acc.y, b4.y), 0.f);
  val.z = fmaxf(fmaf(di, acc.z, b4.z), 0.f);
  val.w = fmaxf(fmaf(di, acc.w, b4.w), 0.f);

  if (!FINAL) {
    if (g == 0) {
      __half2 p0 = __floats2half2_rn(val.x, val.y);
      __half2 p1 = __floats2half2_rn(val.z, val.w);
      __half2 pr[2] = {p0, p1};
      reinterpret_cast<float2*>(OutH)[(size_t)i * 16 + q] =
          *reinterpret_cast<float2*>(pr);
    }
  } else {
    float4 w4 = reinterpret_cast<const float4*>(Wout)[q];
    float r = val.x * w4.x + val.y * w4.y + val.z * w4.z + val.w * w4.w;
    r += __shfl_xor(r, 1); r += __shfl_xor(r, 2);
    r += __shfl_xor(r, 4); r += __shfl_xor(r, 8);
    if (lane == 0) OutF[i] = r + bout[0];
  }
}

extern "C" void kernel_launch(void* const* d_in, const int* in_sizes, int n_in,
                              void* d_out, int out_size, void* d_ws, size_t ws_size,
                              hipStream_t stream) {
  const float* x  = (const float*)d_in[0];
  const int*   ei = (const int*)d_in[1];
  const float* W1 = (const float*)d_in[2];
  const float* b1 = (const float*)d_in[3];
  const float* W2 = (const float*)d_in[4];
  const float* b2 = (const float*)d_in[5];
  const float* W3 = (const float*)d_in[6];
  const float* b3 = (const float*)d_in[7];
  const float* Wo = (const float*)d_in[8];
  const float* bo = (const float*)d_in[9];
  float* out = (float*)d_out;

  char* ws = (char*)d_ws;
  size_t o = 0;
  auto alloc = [&](size_t bytes) {
    size_t r = o;
    o = (o + bytes + 255) & ~(size_t)255;
    return r;
  };
  int*    rs     = (int*)(ws + alloc((size_t)(NN + 1) * 4));
  float*  dis    = (float*)(ws + alloc((size_t)NN * 4));
  int*    flag   = (int*)(ws + alloc(256));
  int*    gbcnt  = (int*)(ws + alloc((size_t)NBUCK * 4));
  int*    bstart = (int*)(ws + alloc((size_t)(NBUCK + 1) * 4));
  int*    bcur   = (int*)(ws + alloc((size_t)NBUCK * BCSTRIDE * 4));
  int*    csr    = (int*)(ws + alloc((size_t)NE * 4));
  __half* A      = (__half*)(ws + alloc((size_t)NN * HID * 2));
  __half* B      = (__half*)(ws + alloc((size_t)NN * HID * 2));
  int*    tmp    = (int*)B;  // aliases B (12.8 MB >= NE*4=6.4 MB); tmp dead
                             // before layer-1 agg fully rewrites B
  (void)ws_size; (void)in_sizes; (void)n_in; (void)out_size;

  const int ABLK = (NN * HID) / 256;    // 25000
  const int GBLK = (NN + 127) / 128;    // 782

  detect_kernel<<<1, 256, 0, stream>>>(ei, flag, gbcnt);
  bhist_kernel<<<400, 256, 0, stream>>>(ei, flag, gbcnt);
  bscan_kernel<<<1, 256, 0, stream>>>(gbcnt, bstart, bcur, rs);
  partA_kernel<<<NWGA, 256, 0, stream>>>(ei, flag, bcur, tmp);
  partB_kernel<<<NBUCK, 256, 0, stream>>>(bstart, tmp, rs, dis, csr);

  // Layer 1: in = x (f32, K=128)
  gemm_kernel<128, false><<<GBLK, 256, 0, stream>>>(x, W1, dis, A);
  agg_kernel<false><<<ABLK, 256, 0, stream>>>(A, rs, csr, dis, b1, nullptr, nullptr, B, nullptr);
  // Layer 2 (fp16 in)
  gemm_kernel<64, true><<<GBLK, 256, 0, stream>>>(B, W2, dis, A);
  agg_kernel<false><<<ABLK, 256, 0, stream>>>(A, rs, csr, dis, b2, nullptr, nullptr, B, nullptr);
  // Layer 3 + fused readout (f32 out)
  gemm_kernel<64, true><<<GBLK, 256, 0, stream>>>(B, W3, dis, A);
  agg_kernel<true><<<ABLK, 256, 0, stream>>>(A, rs, csr, dis, b3, Wo, bo, nullptr, out);
}

// Round 11
// 344.551 us; speedup vs baseline: 2.9417x; 1.2004x over previous
//
#include <hip/hip_runtime.h>
#include <hip/hip_fp16.h>

// GCN node regressor: 3x GCNConv(relu) + linear readout.
// N=100000 nodes, E=1600000 edges, IN=128, HID=64.
//
// v5: MFMA GEMM (fp16 in, f32 acc), zero LDS, zero syncthreads.
//     v4's LDS-tiled vector GEMM measured 55us x3 with 1.16e7 LDS bank
//     conflicts and 23% occupancy. Replaced with mfma_f32_16x16x32_f16:
//     one wave per 16-row tile (NN = 16*6250 exactly), 4 col-tiles, A-frag
//     loaded straight from global, W pre-packed into fragment order (prep).
//     A-load and W-pack share the same k-map (any bijection works if both
//     sides agree); C/D map col=lane&15,row=(lane>>4)*4+reg (HW-verified).
// v4: fp16 storage for node features (halves agg's gather fetch).
// CSR build v3: bhist -> bscan -> partA (per-WG counting sort) -> partB
//     (per-bucket LDS node hist/scan -> rs/dis, local scatter).
// agg: one wave per node; 16-lane group per edge row; f32 accumulate; fused
//     bias+relu; final layer fuses the [64]->1 readout.

#define NN 100000
#define NE 1600000
#define HID 64
#define BSH 9                        // 512 nodes per bucket
#define BNODES (1 << BSH)
#define NBUCK ((NN + BNODES - 1) >> BSH)   // 196
#define BCSTRIDE 16                  // pad bucket cursors to 64B
#define EPT 13                       // edges per thread in partA
#define EW (EPT * 256)               // 3328 edges per WG
#define NWGA ((NE + EW - 1) / EW)    // 481
#define NTILE (NN / 16)              // 6250 row-tiles (exact)

typedef _Float16 half8 __attribute__((ext_vector_type(8)));
typedef float f32x4 __attribute__((ext_vector_type(4)));

// ---------- edge dtype detection + gbcnt zero ----------
__global__ __launch_bounds__(256) void detect_kernel(const int* __restrict__ ei,
                                                     int* __restrict__ flag,
                                                     int* __restrict__ gbcnt) {
  __shared__ int nz;
  if (threadIdx.x == 0) nz = 0;
  if (threadIdx.x < NBUCK) gbcnt[threadIdx.x] = 0;
  __syncthreads();
  if (ei[2 * threadIdx.x + 1] != 0) atomicAdd(&nz, 1);
  __syncthreads();
  if (threadIdx.x == 0) *flag = (nz == 0) ? 1 : 0;  // 1 => int64 layout
}

__device__ __forceinline__ int load_src(const int* ei, int is64, int e) {
  return is64 ? ei[(size_t)2 * e] : ei[e];
}
__device__ __forceinline__ int load_dst(const int* ei, int is64, int e) {
  return is64 ? ei[(size_t)2 * NE + (size_t)2 * e] : ei[(size_t)NE + e];
}

// ---------- coarse bucket histogram ----------
__global__ __launch_bounds__(256) void bhist_kernel(const int* __restrict__ ei,
                                                    const int* __restrict__ flag,
                                                    int* __restrict__ gbcnt) {
  __shared__ int lh[256];
  int t = threadIdx.x;
  lh[t] = 0;
  __syncthreads();
  int is64 = *flag;
  for (int e = blockIdx.x * 256 + t; e < NE; e += gridDim.x * 256) {
    int d = load_dst(ei, is64, e);
    atomicAdd(&lh[d >> BSH], 1);
  }
  __syncthreads();
  if (t < NBUCK && lh[t]) atomicAdd(&gbcnt[t], lh[t]);
}

// 1 WG: exclusive scan of 196 bucket counts -> bstart; seed cursors; rs[NN].
__global__ __launch_bounds__(256) void bscan_kernel(const int* __restrict__ gbcnt,
                                                    int* __restrict__ bstart,
                                                    int* __restrict__ bcur,
                                                    int* __restrict__ rs) {
  __shared__ int sc[256];
  int t = threadIdx.x;
  int v = (t < NBUCK) ? gbcnt[t] : 0;
  sc[t] = v;
  __syncthreads();
  for (int off = 1; off < 256; off <<= 1) {
    int y = (t >= off) ? sc[t - off] : 0;
    __syncthreads();
    sc[t] += y;
    __syncthreads();
  }
  int excl = sc[t] - v;
  if (t < NBUCK) {
    bstart[t] = excl;
    bcur[t * BCSTRIDE] = excl;
  }
  if (t == 0) {
    bstart[NBUCK] = NE;
    rs[NN] = NE;
  }
}

// ---------- partA: per-WG counting sort into bucket-contiguous tmp ----------
// tmp entry: (dl << 17) | s, dl = d & 511 (9b), s < 2^17.
__global__ __launch_bounds__(256) void partA_kernel(const int* __restrict__ ei,
                                                    const int* __restrict__ flag,
                                                    int* __restrict__ bcur,
                                                    int* __restrict__ tmp) {
  __shared__ int lcnt[256];
  __shared__ int sc[256];
  __shared__ int gpos[256];
  __shared__ int stage[EW];
  const int t = threadIdx.x;
  const int base = blockIdx.x * EW;
  const int is64 = *flag;

  int dreg[EPT], sreg[EPT];
#pragma unroll
  for (int u = 0; u < EPT; ++u) {
    int e = base + u * 256 + t;
    int ok = e < NE;
    int ec = ok ? e : (NE - 1);
    dreg[u] = load_dst(ei, is64, ec);
    sreg[u] = load_src(ei, is64, ec);
    if (!ok) dreg[u] = -1;
  }

  lcnt[t] = 0;
  __syncthreads();
#pragma unroll
  for (int u = 0; u < EPT; ++u)
    if (dreg[u] >= 0) atomicAdd(&lcnt[dreg[u] >> BSH], 1);
  __syncthreads();

  sc[t] = lcnt[t];
  __syncthreads();
  for (int off = 1; off < 256; off <<= 1) {
    int y = (t >= off) ? sc[t - off] : 0;
    __syncthreads();
    sc[t] += y;
    __syncthreads();
  }
  if (t < NBUCK && lcnt[t] > 0)
    gpos[t] = atomicAdd(&bcur[t * BCSTRIDE], lcnt[t]);
  sc[t] -= lcnt[t];
  __syncthreads();

#pragma unroll
  for (int u = 0; u < EPT; ++u) {
    if (dreg[u] >= 0) {
      int b = dreg[u] >> BSH;
      int p = atomicAdd(&sc[b], 1);
      stage[p] = ((dreg[u] & (BNODES - 1)) << 17) | sreg[u];
    }
  }
  __syncthreads();
  int total = base + EW <= NE ? EW : (NE - base);
  for (int idx = t; idx < total; idx += 256) {
    int lo = 0, hi = NBUCK - 1;
    while (lo < hi) {
      int mid = (lo + hi) >> 1;
      if (sc[mid] > idx) hi = mid; else lo = mid + 1;
    }
    int b = lo;
    int off_b = sc[b] - lcnt[b];
    tmp[gpos[b] + (idx - off_b)] = stage[idx];
  }
}

// ---------- partB: per-bucket node hist/scan -> rs, dis; scatter csr ----------
__global__ __launch_bounds__(256) void partB_kernel(const int* __restrict__ bstart,
                                                    const int* __restrict__ tmp,
                                                    int* __restrict__ rs,
                                                    float* __restrict__ dis,
                                                    int* __restrict__ csr) {
  __shared__ int cnt[BNODES];
  __shared__ int sc[BNODES];
  __shared__ int t2[256];
  const int b = blockIdx.x;
  const int t = threadIdx.x;
  const int nbase = b << BSH;
  const int e0 = bstart[b], e1 = bstart[b + 1];

  cnt[t] = 0; cnt[t + 256] = 0;
  __syncthreads();
  for (int e = e0 + t; e < e1; e += 256)
    atomicAdd(&cnt[tmp[e] >> 17], 1);
  __syncthreads();

  int a0 = cnt[2 * t], a1 = cnt[2 * t + 1];
  t2[t] = a0 + a1;
  __syncthreads();
  for (int off = 1; off < 256; off <<= 1) {
    int y = (t >= off) ? t2[t - off] : 0;
    __syncthreads();
    t2[t] += y;
    __syncthreads();
  }
  int pbase = t2[t] - (a0 + a1);
  sc[2 * t] = pbase;
  sc[2 * t + 1] = pbase + a0;
  __syncthreads();

#pragma unroll
  for (int rep = 0; rep < 2; ++rep) {
    int j = t + rep * 256;
    int n = nbase + j;
    if (n < NN) {
      rs[n] = e0 + sc[j];
      dis[n] = rsqrtf((float)cnt[j] + 1.0f);
    }
    sc[j] += e0;
  }
  __syncthreads();

  for (int e = e0 + t; e < e1; e += 256) {
    int p = tmp[e];
    int pos = atomicAdd(&sc[p >> 17], 1);
    csr[pos] = p & 0x1FFFF;
  }
}

// ---------- prep: pack W (f32 [K][64]) into MFMA B-fragment order, fp16 ----------
// Wf[((ct*KS + ks)*64 + l)*8 + j] = W[(ks*32 + (l>>4)*8 + j)*64 + ct*16 + (l&15)]
// (k-map (l>>4)*8+j matches the A-load; C/D map is the HW-verified one.)
__device__ __forceinline__ void pack_one(int e, int KS, const float* __restrict__ W,
                                         _Float16* __restrict__ Wf) {
  int j = e & 7;
  int l = (e >> 3) & 63;
  int rest = e >> 9;
  int ks = rest % KS;
  int ct = rest / KS;
  int k = ks * 32 + (l >> 4) * 8 + j;
  int c = ct * 16 + (l & 15);
  Wf[e] = (_Float16)W[k * 64 + c];
}

__global__ __launch_bounds__(256) void prep_kernel(const float* __restrict__ W1,
                                                   const float* __restrict__ W2,
                                                   const float* __restrict__ W3,
                                                   _Float16* __restrict__ Wf1,
                                                   _Float16* __restrict__ Wf2,
                                                   _Float16* __restrict__ Wf3) {
  int t = blockIdx.x * 256 + threadIdx.x;
  if (t < 8192) pack_one(t, 4, W1, Wf1);                 // 4ct * 4ks * 512
  else if (t < 12288) pack_one(t - 8192, 2, W2, Wf2);    // 4ct * 2ks * 512
  else if (t < 16384) pack_one(t - 12288, 2, W3, Wf3);
}

// ---------- GEMM v5 (MFMA): G[r][c] = fp16( dis[r] * sum_k X[r][k]*W[k][c] ) ----
// One wave per 16-row tile; 4 col-tiles of 16; K-loop in steps of 32.
// No LDS, no barriers. A: lane holds X[tile+（l&15)][ks*32+(l>>4)*8 ..+8).
template <int K, bool HALF_IN>
__global__ __launch_bounds__(256) void gemm_kernel(const void* __restrict__ Xv,
                                                   const _Float16* __restrict__ Wf,
                                                   const float* __restrict__ dis,
                                                   __half* __restrict__ G) {
  constexpr int KS = K / 32;
  int wv = (blockIdx.x << 2) + (threadIdx.x >> 6);   // tile index
  if (wv >= NTILE) return;
  const int l = threadIdx.x & 63;
  const int lm = l & 15, lg = l >> 4;
  const int row_a = wv * 16 + lm;

  f32x4 acc[4];
#pragma unroll
  for (int ct = 0; ct < 4; ++ct) acc[ct] = (f32x4){0.f, 0.f, 0.f, 0.f};

#pragma unroll
  for (int ks = 0; ks < KS; ++ks) {
    half8 a;
    if constexpr (HALF_IN) {
      a = *reinterpret_cast<const half8*>((const _Float16*)Xv +
                                          (size_t)row_a * K + ks * 32 + lg * 8);
    } else {
      const float* xp = (const float*)Xv + (size_t)row_a * K + ks * 32 + lg * 8;
      float4 u = *reinterpret_cast<const float4*>(xp);
      float4 v = *reinterpret_cast<const float4*>(xp + 4);
      a = (half8){(_Float16)u.x, (_Float16)u.y, (_Float16)u.z, (_Float16)u.w,
                  (_Float16)v.x, (_Float16)v.y, (_Float16)v.z, (_Float16)v.w};
    }
#pragma unroll
    for (int ct = 0; ct < 4; ++ct) {
      half8 b = *reinterpret_cast<const half8*>(Wf + (((ct * KS + ks) << 6) + l) * 8);
      acc[ct] = __builtin_amdgcn_mfma_f32_16x16x32_f16(a, b, acc[ct], 0, 0, 0);
    }
  }

  // epilogue: D col = lane&15, row = (lane>>4)*4 + reg  [HW-verified map]
#pragma unroll
  for (int reg = 0; reg < 4; ++reg) {
    int row = wv * 16 + lg * 4 + reg;
    float di = dis[row];
#pragma unroll
    for (int ct = 0; ct < 4; ++ct) {
      G[(size_t)row * HID + ct * 16 + lm] = __float2half(acc[ct][reg] * di);
    }
  }
}

// ---------- aggregation: one wave per node, 4 edges per pass, fp16 rows ----------
template <bool FINAL>
__global__ __launch_bounds__(256) void agg_kernel(const __half* __restrict__ G,
                                                  const int* __restrict__ rs,
                                                  const int* __restrict__ csr,
                                                  const float* __restrict__ dis,
                                                  const float* __restrict__ bias,
                                                  const float* __restrict__ Wout,
                                                  const float* __restrict__ bout,
                                                  __half* __restrict__ OutH,
                                                  float* __restrict__ OutF) {
  int gtid = blockIdx.x * 256 + threadIdx.x;
  int i = gtid >> 6;
  if (i >= NN) return;
  int lane = threadIdx.x & 63;
  int g = lane >> 4, q = lane & 15;
  const float2* G2 = reinterpret_cast<const float2*>(G);  // 16 float2 per row
  int s0 = rs[i], s1 = rs[i + 1];

  float4 acc = make_float4(0.f, 0.f, 0.f, 0.f);
  auto addrow = [&](int src) {
    float2 raw = G2[(size_t)src * 16 + q];
    const __half2* hp = reinterpret_cast<const __half2*>(&raw);
    float2 a = __half22float2(hp[0]);
    float2 b = __half22float2(hp[1]);
    acc.x += a.x; acc.y += a.y; acc.z += b.x; acc.w += b.y;
  };
  if (g == 0) addrow(i);  // self-loop term, counted once
  int e = s0;
  for (; e + 8 <= s1; e += 8) {
    int sA = csr[e + g];
    int sB = csr[e + 4 + g];
    addrow(sA);
    addrow(sB);
  }
  for (; e < s1; e += 4) {
    int ee = e + g;
    if (ee < s1) addrow(csr[ee]);
  }
  acc.x += __shfl_xor(acc.x, 16); acc.y += __shfl_xor(acc.y, 16);
  acc.z += __shfl_xor(acc.z, 16); acc.w += __shfl_xor(acc.w, 16);
  acc.x += __shfl_xor(acc.x, 32); acc.y += __shfl_xor(acc.y, 32);
  acc.z += __shfl_xor(acc.z, 32); acc.w += __shfl_xor(acc.w, 32);

  float di = dis[i];
  float4 b4 = reinterpret_cast<const float4*>(bias)[q];
  float4 val;
  val.x = fmaxf(fmaf(di, acc.x, b4.x), 0.f);
  val.y = fmaxf(fmaf(di, acc.y, b4.y), 0.f);
  val.z = fmaxf(fmaf(di, acc.z, b4.z), 0.f);
  val.w = fmaxf(fmaf(di, acc.w, b4.w), 0.f);

  if (!FINAL) {
    if (g == 0) {
      __half2 p0 = __floats2half2_rn(val.x, val.y);
      __half2 p1 = __floats2half2_rn(val.z, val.w);
      __half2 pr[2] = {p0, p1};
      reinterpret_cast<float2*>(OutH)[(size_t)i * 16 + q] =
          *reinterpret_cast<float2*>(pr);
    }
  } else {
    float4 w4 = reinterpret_cast<const float4*>(Wout)[q];
    float r = val.x * w4.x + val.y * w4.y + val.z * w4.z + val.w * w4.w;
    r += __shfl_xor(r, 1); r += __shfl_xor(r, 2);
    r += __shfl_xor(r, 4); r += __shfl_xor(r, 8);
    if (lane == 0) OutF[i] = r + bout[0];
  }
}

extern "C" void kernel_launch(void* const* d_in, const int* in_sizes, int n_in,
                              void* d_out, int out_size, void* d_ws, size_t ws_size,
                              hipStream_t stream) {
  const float* x  = (const float*)d_in[0];
  const int*   ei = (const int*)d_in[1];
  const float* W1 = (const float*)d_in[2];
  const float* b1 = (const float*)d_in[3];
  const float* W2 = (const float*)d_in[4];
  const float* b2 = (const float*)d_in[5];
  const float* W3 = (const float*)d_in[6];
  const float* b3 = (const float*)d_in[7];
  const float* Wo = (const float*)d_in[8];
  const float* bo = (const float*)d_in[9];
  float* out = (float*)d_out;

  char* ws = (char*)d_ws;
  size_t o = 0;
  auto alloc = [&](size_t bytes) {
    size_t r = o;
    o = (o + bytes + 255) & ~(size_t)255;
    return r;
  };
  int*      rs     = (int*)(ws + alloc((size_t)(NN + 1) * 4));
  float*    dis    = (float*)(ws + alloc((size_t)NN * 4));
  int*      flag   = (int*)(ws + alloc(256));
  int*      gbcnt  = (int*)(ws + alloc((size_t)NBUCK * 4));
  int*      bstart = (int*)(ws + alloc((size_t)(NBUCK + 1) * 4));
  int*      bcur   = (int*)(ws + alloc((size_t)NBUCK * BCSTRIDE * 4));
  _Float16* Wf1    = (_Float16*)(ws + alloc(8192 * 2));
  _Float16* Wf2    = (_Float16*)(ws + alloc(4096 * 2));
  _Float16* Wf3    = (_Float16*)(ws + alloc(4096 * 2));
  int*      csr    = (int*)(ws + alloc((size_t)NE * 4));
  __half*   A      = (__half*)(ws + alloc((size_t)NN * HID * 2));
  __half*   B      = (__half*)(ws + alloc((size_t)NN * HID * 2));
  int*      tmp    = (int*)B;  // aliases B (12.8 MB >= NE*4=6.4 MB); tmp dead
                               // before layer-1 agg fully rewrites B
  (void)ws_size; (void)in_sizes; (void)n_in; (void)out_size;

  const int ABLK = (NN * HID) / 256;       // 25000
  const int GBLK = (NTILE + 3) / 4;        // 1563 (4 waves/block, 1 tile/wave)

  detect_kernel<<<1, 256, 0, stream>>>(ei, flag, gbcnt);
  bhist_kernel<<<400, 256, 0, stream>>>(ei, flag, gbcnt);
  bscan_kernel<<<1, 256, 0, stream>>>(gbcnt, bstart, bcur, rs);
  partA_kernel<<<NWGA, 256, 0, stream>>>(ei, flag, bcur, tmp);
  partB_kernel<<<NBUCK, 256, 0, stream>>>(bstart, tmp, rs, dis, csr);
  prep_kernel<<<64, 256, 0, stream>>>(W1, W2, W3, Wf1, Wf2, Wf3);

  // Layer 1: in = x (f32, K=128)
  gemm_kernel<128, false><<<GBLK, 256, 0, stream>>>(x, Wf1, dis, A);
  agg_kernel<false><<<ABLK, 256, 0, stream>>>(A, rs, csr, dis, b1, nullptr, nullptr, B, nullptr);
  // Layer 2 (fp16 in)
  gemm_kernel<64, true><<<GBLK, 256, 0, stream>>>(B, Wf2, dis, A);
  agg_kernel<false><<<ABLK, 256, 0, stream>>>(A, rs, csr, dis, b2, nullptr, nullptr, B, nullptr);
  // Layer 3 + fused readout (f32 out)
  gemm_kernel<64, true><<<GBLK, 256, 0, stream>>>(B, Wf3, dis, A);
  agg_kernel<true><<<ABLK, 256, 0, stream>>>(A, rs, csr, dis, b3, Wo, bo, nullptr, out);
}